// Round 14
// baseline (217.541 us; speedup 1.0000x reference)
//
#include <hip/hip_runtime.h>
#include <hip/hip_bf16.h>
#include <hip/hip_cooperative_groups.h>

namespace cg = cooperative_groups;

typedef _Float16 h8 __attribute__((ext_vector_type(8)));
typedef _Float16 h4 __attribute__((ext_vector_type(4)));
typedef _Float16 h2 __attribute__((ext_vector_type(2)));
typedef __fp16 fp16x2 __attribute__((ext_vector_type(2)));
typedef float f4 __attribute__((ext_vector_type(4)));

#define S_LEN 2048
#define EMB 1024
#define NH 16
#define DH 64

__device__ __forceinline__ void async_copy16(const void* g, void* l) {
  __builtin_amdgcn_global_load_lds(
      (const __attribute__((address_space(1))) void*)g,
      (__attribute__((address_space(3))) void*)l, 16, 0, 0);
}

__device__ __forceinline__ f4 mfma16(h8 a, h8 b, f4 c) {
  return __builtin_amdgcn_mfma_f32_16x16x32_f16(a, b, c, 0, 0, 0);
}

__device__ __forceinline__ h2 cvt_pk(float a, float b) {
  const fp16x2 r = __builtin_amdgcn_cvt_pkrtz(a, b);
  return __builtin_bit_cast(h2, r);
}

// ------- fused prep: x->f16 cast + 7 weight transposes + gmask compaction scan ----
__global__ __launch_bounds__(256) void prep_kernel(
    const float* __restrict__ x, const float* w0, const float* w1, const float* w2,
    const float* w3, const float* w4, const float* w5, const float* w6,
    _Float16* __restrict__ xh, _Float16* __restrict__ Wtb,
    const int* __restrict__ gmask, int* __restrict__ qsel, int* __restrict__ qcnt) {
  const int bid = blockIdx.x;
  if (bid < 2048) {
    const int i = bid * 256 + threadIdx.x;      // *4 elements
    const float4 v = *(const float4*)&x[(long)i * 4];
    h4 o;
    o.x = (_Float16)v.x; o.y = (_Float16)v.y; o.z = (_Float16)v.z; o.w = (_Float16)v.w;
    *(h4*)&xh[(long)i * 4] = o;
    return;
  }
  if (bid < 9216) {
    const int b2 = bid - 2048;
    const int z = b2 >> 10, rem = b2 & 1023;
    const float* W = w0;
    switch (z) {
      case 1: W = w1; break; case 2: W = w2; break; case 3: W = w3; break;
      case 4: W = w4; break; case 5: W = w5; break; case 6: W = w6; break;
      default: break;
    }
    __shared__ float t[32][33];
    const int bk = (rem & 31) * 32, bn = (rem >> 5) * 32;
    const int tx = threadIdx.x & 31, ty = threadIdx.x >> 5;   // 32 x 8
    #pragma unroll
    for (int i = 0; i < 4; ++i)
      t[ty + i * 8][tx] = W[(long)(bk + ty + i * 8) * 1024 + bn + tx];
    __syncthreads();
    _Float16* o = Wtb + (long)z * 1048576;
    #pragma unroll
    for (int i = 0; i < 4; ++i)
      o[(long)(bn + ty + i * 8) * 1024 + bk + tx] = (_Float16)t[tx][ty + i * 8];
    return;
  }
  // gmask==1 compaction scan (single block)
  const int t = threadIdx.x;
  int m8[8], cnt8 = 0;
  #pragma unroll
  for (int j = 0; j < 8; ++j) {
    m8[j] = gmask[t * 8 + j];
    cnt8 += (m8[j] == 1);
  }
  __shared__ int sc[256];
  sc[t] = cnt8;
  __syncthreads();
  for (int off = 1; off < 256; off <<= 1) {
    const int v = (t >= off) ? sc[t - off] : 0;
    __syncthreads();
    sc[t] += v;
    __syncthreads();
  }
  int base = sc[t] - cnt8;
  #pragma unroll
  for (int j = 0; j < 8; ++j)
    if (m8[j] == 1) qsel[base++] = t * 8 + j;
  if (t == 255) qcnt[0] = sc[255];
}

// ---------------- 8-phase 256x256 deep-pipelined GEMM (projection) ----------------
__global__ __launch_bounds__(512, 2) void gemm256_kernel(
    const _Float16* __restrict__ A, const _Float16* __restrict__ Bt,
    _Float16* __restrict__ Aq, _Float16* __restrict__ Ak,
    _Float16* __restrict__ proj234, _Float16* __restrict__ vgT) {
  const int bid = blockIdx.x;                 // 192 blocks
  const int bxx = (bid >> 3) & 7;             // m-block 0..7
  const int byy = (bid & 7) * 3 + (bid >> 6); // n-block 0..23, XCD-pinned
  const int bm = bxx * 256, bn = byy * 256;

  __shared__ alignas(16) _Float16 As[2][2][8192];
  __shared__ alignas(16) _Float16 Bs[2][2][8192];

  const int tid = threadIdx.x;
  const int w = tid >> 6, l = tid & 63;
  const int lo = l & 15, hi = l >> 4;
  const int wm = w >> 2, wn = w & 3;
  const int srow = tid >> 3;                  // 0..63
  const int kseg = (tid & 7) ^ (srow & 7);    // source-preswizzled k-seg

  const _Float16* Bb = Bt + (long)(byy >> 2) * 1048576 + (long)(bn & 1023) * 1024;

#define STG_A(db, half, tt) do {                                                     \
    const int t_ = (tt) < 15 ? (tt) : 15;                                            \
    const _Float16* s_ = A + (long)(bm + (half) * 128 + srow) * 1024 + t_ * 64 + kseg * 8; \
    async_copy16(s_, &As[db][half][w * 512]);                                        \
    async_copy16(s_ + 65536, &As[db][half][4096 + w * 512]);                         \
  } while (0)
#define STG_B(db, half, tt) do {                                                     \
    const int t_ = (tt) < 15 ? (tt) : 15;                                            \
    const _Float16* s_ = Bb + (long)((half) * 128 + srow) * 1024 + t_ * 64 + kseg * 8; \
    async_copy16(s_, &Bs[db][half][w * 512]);                                        \
    async_copy16(s_ + 65536, &Bs[db][half][4096 + w * 512]);                         \
  } while (0)
#define LDA(db, mg) do { _Pragma("unroll")                                           \
    for (int fr = 0; fr < 4; ++fr) {                                                 \
      const int rr = wm * 64 + fr * 16 + lo;                                         \
      _Pragma("unroll") for (int kk = 0; kk < 2; ++kk)                               \
        af[fr][kk] = *(const h8*)&As[db][mg][rr * 64 + (((kk * 4 + hi) ^ (rr & 7)) * 8)]; \
    } } while (0)
#define LDB(db, ng) do { _Pragma("unroll")                                           \
    for (int fc = 0; fc < 2; ++fc) {                                                 \
      const int rr = wn * 32 + fc * 16 + lo;                                         \
      _Pragma("unroll") for (int kk = 0; kk < 2; ++kk)                               \
        bf[ng][fc][kk] = *(const h8*)&Bs[db][ng][rr * 64 + (((kk * 4 + hi) ^ (rr & 7)) * 8)]; \
    } } while (0)
#define MFMA_PH(mg, ng) do {                                                         \
    __builtin_amdgcn_s_setprio(1);                                                   \
    _Pragma("unroll") for (int fr = 0; fr < 4; ++fr)                                 \
      _Pragma("unroll") for (int fc = 0; fc < 2; ++fc) {                             \
        acc[mg][fr][ng][fc] = mfma16(af[fr][0], bf[ng][fc][0], acc[mg][fr][ng][fc]); \
        acc[mg][fr][ng][fc] = mfma16(af[fr][1], bf[ng][fc][1], acc[mg][fr][ng][fc]); \
      }                                                                              \
    __builtin_amdgcn_s_setprio(0);                                                   \
  } while (0)
#define BARR do { asm volatile("" ::: "memory"); __builtin_amdgcn_s_barrier();       \
                  asm volatile("" ::: "memory"); } while (0)
#define VM8 asm volatile("s_waitcnt vmcnt(8)" ::: "memory")

  const f4 zero = {0.f, 0.f, 0.f, 0.f};
  f4 acc[2][4][2][2];
  #pragma unroll
  for (int a_ = 0; a_ < 2; ++a_)
    #pragma unroll
    for (int b_ = 0; b_ < 4; ++b_)
      #pragma unroll
      for (int c_ = 0; c_ < 2; ++c_)
        #pragma unroll
        for (int d_ = 0; d_ < 2; ++d_) acc[a_][b_][c_][d_] = zero;
  h8 af[4][2];
  h8 bf[2][2][2];

  STG_A(0, 0, 0); STG_B(0, 0, 0); STG_A(0, 1, 0); STG_B(0, 1, 0);
  STG_A(1, 0, 1); STG_B(1, 0, 1); STG_A(1, 1, 1);
  asm volatile("s_waitcnt vmcnt(4)" ::: "memory");   // covers t0 A0,B0,A1,B1 + t1.A0
  BARR;

  for (int i = 0; i < 8; ++i) {
    const int t2 = 2 * i + 2, t3 = 2 * i + 3;
    LDA(0, 0); LDB(0, 0); STG_B(1, 1, 2 * i + 1); MFMA_PH(0, 0); VM8; BARR;
    LDB(0, 1); STG_A(0, 0, t2); MFMA_PH(0, 1); BARR;
    LDA(0, 1); STG_B(0, 0, t2); MFMA_PH(1, 0); BARR;
    STG_A(0, 1, t2); MFMA_PH(1, 1); VM8; BARR;
    LDA(1, 0); LDB(1, 0); STG_B(0, 1, t2); MFMA_PH(0, 0); VM8; BARR;
    LDB(1, 1); STG_A(1, 0, t3); MFMA_PH(0, 1); BARR;
    LDA(1, 1); STG_B(1, 0, t3); MFMA_PH(1, 0); BARR;
    STG_A(1, 1, t3); MFMA_PH(1, 1); VM8; BARR;
  }

  // epilogue: per-slab consumer layout
  const int slabv = byy >> 2;
  #pragma unroll
  for (int mg = 0; mg < 2; ++mg)
    #pragma unroll
    for (int fr = 0; fr < 4; ++fr) {
      const int row0 = bm + mg * 128 + wm * 64 + fr * 16 + hi * 4;
      #pragma unroll
      for (int ng = 0; ng < 2; ++ng)
        #pragma unroll
        for (int fc = 0; fc < 2; ++fc) {
          const int colg = bn + ng * 128 + wn * 32 + fc * 16 + lo;
          const int e = colg & 1023;
          if (slabv <= 1) {
            _Float16* dst = (slabv == 0) ? Aq : Ak;
            #pragma unroll
            for (int r = 0; r < 4; ++r) {
              const int s = row0 + r;
              const long off = (long)(((s >> 7) * 256 + (s & 15) * 16 + (e >> 6))) * 512
                               + ((s >> 4) & 7) * 64 + (e & 63);
              dst[off] = (_Float16)acc[mg][fr][ng][fc][r];
            }
          } else if (slabv == 5) {
            const h2 a = cvt_pk(acc[mg][fr][ng][fc][0], acc[mg][fr][ng][fc][1]);
            const h2 b = cvt_pk(acc[mg][fr][ng][fc][2], acc[mg][fr][ng][fc][3]);
            const h4 v4 = {a[0], a[1], b[0], b[1]};
            *(h4*)&vgT[(long)e * 2048 + row0] = v4;
          } else {
            _Float16* cp = proj234 + (long)(slabv - 2) * 2097152 + (long)row0 * 1024 + e;
            #pragma unroll
            for (int r = 0; r < 4; ++r)
              cp[(long)r * 1024] = (_Float16)acc[mg][fr][ng][fc][r];
          }
        }
    }
#undef STG_A
#undef STG_B
#undef LDA
#undef LDB
#undef MFMA_PH
#undef BARR
#undef VM8
}

// ================= tail phases (shared device code) =================

__device__ __forceinline__ void phaseA_item(
    char* smem, int bx, int tid,
    const _Float16* __restrict__ Q, const _Float16* __restrict__ Km,
    const _Float16* __restrict__ Vt, const int* __restrict__ qsel,
    const int* __restrict__ qcnt, _Float16* __restrict__ ctx,
    _Float16* __restrict__ pO, float2* __restrict__ ml,
    const _Float16* __restrict__ Aq, const _Float16* __restrict__ Ak,
    _Float16* __restrict__ P, const _Float16* __restrict__ vl,
    float* __restrict__ Vall, float* __restrict__ Vtail) {
  if (bx >= 1088) {
    // ---- V column sums per head ----
    const int hh = bx - 1088;
    const int d = tid & 63, g = tid >> 6;
    float sall = 0.f, shead = 0.f;
    for (int i = 0; i < 32; ++i) {
      const int ro = g * 32 + i;  // 0..127
      const _Float16* base = vl + (long)(hh * 128 + ro) * 1024 + d;
      #pragma unroll
      for (int j = 0; j < 16; ++j) {
        const float v = (float)base[j * 64];
        sall += v;
        if (ro < 16) shead += v;
      }
    }
    float* sA = (float*)smem;            // [4][64]
    float* sH = (float*)(smem + 1024);   // [4][64]
    sA[g * 64 + d] = sall; sH[g * 64 + d] = shead;
    __syncthreads();
    if (g == 0) {
      const float a = sA[d] + sA[64 + d] + sA[128 + d] + sA[192 + d];
      const float hsum = sH[d] + sH[64 + d] + sH[128 + d] + sH[192 + d];
      Vall[hh * 64 + d] = a;
      Vtail[hh * 64 + d] = a - hsum;
    }
    __syncthreads();
    return;
  }

  if (bx >= 1024) {
    // ---- P-gemm: P[h] = Aq[h] * Ak[h]^T, 128^2 tile, K=512 ----
    const int b = bx - 1024;
    const int bzz = b >> 2, bxx = (b >> 1) & 1, byy = b & 1;
    const _Float16* Ab = Aq + (long)bzz * 131072;
    const _Float16* Bb = Ak + (long)bzz * 131072;
    const int bm = bxx * 128, bn = byy * 128;
    _Float16* As = (_Float16*)smem;             // 128*64
    _Float16* Bs = (_Float16*)(smem + 16384);   // 128*64
    const int w = tid >> 6, l = tid & 63;
    const int lo = l & 15, hi = l >> 4;
    const int wr = (w >> 1) * 64, wc = (w & 1) * 64;
    const int srow = l >> 3, ssp = l & 7;
    const int ssl = ssp ^ (srow & 7);

    const f4 zero = {0.f, 0.f, 0.f, 0.f};
    f4 acc[4][4];
    #pragma unroll
    for (int m = 0; m < 4; ++m)
      #pragma unroll
      for (int n = 0; n < 4; ++n) acc[m][n] = zero;

    for (int k0 = 0; k0 < 512; k0 += 64) {
      #pragma unroll
      for (int i = 0; i < 4; ++i) {
        const int chunk = w + i * 4;
        async_copy16(&Ab[(long)(bm + chunk * 8 + srow) * 512 + k0 + ssl * 8], &As[chunk * 512]);
        async_copy16(&Bb[(long)(bn + chunk * 8 + srow) * 512 + k0 + ssl * 8], &Bs[chunk * 512]);
      }
      __syncthreads();
      #pragma unroll
      for (int kk = 0; kk < 2; ++kk) {
        h8 af[4], bff[4];
        #pragma unroll
        for (int m = 0; m < 4; ++m) {
          const int r = wr + m * 16 + lo;
          af[m] = *(const h8*)&As[r * 64 + (((kk * 4 + hi) ^ (r & 7)) * 8)];
        }
        #pragma unroll
        for (int n = 0; n < 4; ++n) {
          const int r = wc + n * 16 + lo;
          bff[n] = *(const h8*)&Bs[r * 64 + (((kk * 4 + hi) ^ (r & 7)) * 8)];
        }
        #pragma unroll
        for (int m = 0; m < 4; ++m)
          #pragma unroll
          for (int n = 0; n < 4; ++n)
            acc[m][n] = mfma16(af[m], bff[n], acc[m][n]);
      }
      __syncthreads();
    }
    #pragma unroll
    for (int m = 0; m < 4; ++m) {
      const int row0 = bm + wr + m * 16 + hi * 4;
      #pragma unroll
      for (int n = 0; n < 4; ++n) {
        const int col = bn + wc + n * 16 + lo;
        #pragma unroll
        for (int r = 0; r < 4; ++r)
          P[(long)bzz * 65536 + (long)(row0 + r) * 256 + col] = (_Float16)acc[m][n][r];
      }
    }
    return;
  }

  // ---- flash ----
  const int h = bx & 15;
  const int v = bx >> 4;               // 0..63
  const int tile = 31 - (v >> 1);      // heavy-first
  const int chunk = v & 1;
  int cnt = qcnt[0];
  cnt = cnt < 1 ? 1 : (cnt > 2048 ? 2048 : cnt);   // rocprof-replay poison guard
  if (tile * 64 >= cnt) return;
  const int L = (qsel[min(tile * 64 + 63, cnt - 1)] & 2047) + 1;
  const int ntot = (L + 63) >> 6;
  const bool chunked = (ntot > 16);
  if (!chunked && chunk) return;
  const int nsplit = chunked ? ((ntot + 1) >> 1) : ntot;
  const int t0 = chunk ? nsplit : 0;
  const int t1 = chunk ? ntot : nsplit;

  const int w = tid >> 6, l = tid & 63;
  const int lo = l & 15, hi = l >> 4;
  const int row = tile * 64 + w * 16 + lo;
  const int qg = qsel[min(row, cnt - 1)] & 2047;   // orig seq position

  _Float16* KsB = (_Float16*)smem;             // [2][4096]
  _Float16* VsB = (_Float16*)(smem + 16384);   // [2][4096]
  _Float16* ps = (_Float16*)(smem + 32768) + w * 1280;  // [16 q][80]

  const int rl = tid >> 3;              // 0..31
  const int ssl = (tid & 7) ^ (rl & 7); // source-preswizzled k-seg

#define STAGE(b, t)                                                                   \
  do {                                                                                \
    async_copy16(&Km[(long)((t) * 64 + rl) * EMB + h * DH + ssl * 8],                 \
                 &KsB[(b) * 4096 + (w * 8) * 64]);                                    \
    async_copy16(&Km[(long)((t) * 64 + 32 + rl) * EMB + h * DH + ssl * 8],            \
                 &KsB[(b) * 4096 + (w * 8 + 32) * 64]);                               \
    async_copy16(&Vt[(long)(h * DH + rl) * S_LEN + (t) * 64 + ssl * 8],               \
                 &VsB[(b) * 4096 + (w * 8) * 64]);                                    \
    async_copy16(&Vt[(long)(h * DH + 32 + rl) * S_LEN + (t) * 64 + ssl * 8],          \
                 &VsB[(b) * 4096 + (w * 8 + 32) * 64]);                               \
  } while (0)

  h8 qf[2];
  #pragma unroll
  for (int kk = 0; kk < 2; ++kk)
    qf[kk] = *(const h8*)&Q[(long)qg * EMB + h * DH + kk * 32 + hi * 8];

  const f4 zero = {0.f, 0.f, 0.f, 0.f};
  f4 o[4];
  #pragma unroll
  for (int nd = 0; nd < 4; ++nd) o[nd] = zero;
  float mr = -1e30f, lr = 0.f;
  const float SC = 0.125f * 1.44269504f;   // scale folded into log2 domain

  STAGE(0, t0);
  __syncthreads();
  int cur = 0;

  for (int t = t0; t < t1; ++t) {
    if (t + 1 < t1) STAGE(cur ^ 1, t + 1);   // prefetch next tile (async)

    const _Float16* ks = KsB + cur * 4096;
    const _Float16* vs = VsB + cur * 4096;

    // ---- QK^T (S^T = K x Q) ----
    __builtin_amdgcn_s_setprio(1);
    f4 s[4];
    #pragma unroll
    for (int n = 0; n < 4; ++n) {
      s[n] = zero;
      #pragma unroll
      for (int kk = 0; kk < 2; ++kk) {
        const int r = n * 16 + lo;
        const h8 kf = *(const h8*)&ks[r * 64 + (((kk * 4 + hi) ^ (lo & 7)) * 8)];
        s[n] = mfma16(kf, qf[kk], s[n]);
      }
    }
    __builtin_amdgcn_s_setprio(0);

    // ---- online softmax (log2 domain), q lane-local, causal vs qg ----
    float sv[16];
    float tm = -1e30f;
    #pragma unroll
    for (int n = 0; n < 4; ++n)
      #pragma unroll
      for (int r = 0; r < 4; ++r) {
        float vv = s[n][r] * SC;
        if ((t * 64 + n * 16 + hi * 4 + r) > qg) vv = -1e30f;
        sv[n * 4 + r] = vv;
        tm = fmaxf(tm, vv);
      }
    tm = fmaxf(tm, __shfl_xor(tm, 16));
    tm = fmaxf(tm, __shfl_xor(tm, 32));
    const float mn = fmaxf(mr, tm);
    const float c = exp2f(mr - mn);
    mr = mn;
    float psum = 0.f;
    #pragma unroll
    for (int i = 0; i < 16; ++i) {
      sv[i] = exp2f(sv[i] - mr);
      psum += sv[i];
    }
    psum += __shfl_xor(psum, 16);
    psum += __shfl_xor(psum, 32);
    lr = lr * c + psum;

    // ---- pack P^T -> ps[q][key] (row stride 80, XOR-swizzled 16B segs) ----
    #pragma unroll
    for (int n = 0; n < 4; ++n) {
      const int seg = (2 * n + (hi >> 1)) ^ (lo & 7);
      const int base = lo * 80 + seg * 8 + (hi & 1) * 4;
      *(h2*)&ps[base] = cvt_pk(sv[n * 4 + 0], sv[n * 4 + 1]);
      *(h2*)&ps[base + 2] = cvt_pk(sv[n * 4 + 2], sv[n * 4 + 3]);
    }
    h8 pb[2];
    #pragma unroll
    for (int kk = 0; kk < 2; ++kk)
      pb[kk] = *(const h8*)&ps[lo * 80 + (((kk * 4 + hi) ^ (lo & 7)) * 8)];

    // ---- PV: O^T[d][q] += V^T x P ----
    __builtin_amdgcn_s_setprio(1);
    #pragma unroll
    for (int nd = 0; nd < 4; ++nd) {
      #pragma unroll
      for (int r = 0; r < 4; ++r) o[nd][r] *= c;
      #pragma unroll
      for (int kk = 0; kk < 2; ++kk) {
        const int rr = nd * 16 + lo;
        const h8 vf = *(const h8*)&vs[rr * 64 + (((kk * 4 + hi) ^ (lo & 7)) * 8)];
        o[nd] = mfma16(vf, pb[kk], o[nd]);
      }
    }
    __builtin_amdgcn_s_setprio(0);

    __syncthreads();   // drains prefetch + guards buffer reuse
    cur ^= 1;
  }
#undef STAGE

  if (chunked) {
    const int slot = (h * 32 + tile) * 2 + chunk;
    _Float16* po = pO + (long)slot * 4096 + (w * 16 + lo) * 64;
    #pragma unroll
    for (int nd = 0; nd < 4; ++nd) {
      const h2 a = cvt_pk(o[nd][0], o[nd][1]);
      const h2 b = cvt_pk(o[nd][2], o[nd][3]);
      const h4 v4 = {a[0], a[1], b[0], b[1]};
      *(h4*)&po[nd * 16 + hi * 4] = v4;
    }
    if (hi == 0) ml[slot * 64 + w * 16 + lo] = make_float2(mr, lr);
  } else if (row < cnt) {
    const float inv = 1.f / lr;
    #pragma unroll
    for (int nd = 0; nd < 4; ++nd) {
      const h2 a = cvt_pk(o[nd][0] * inv, o[nd][1] * inv);
      const h2 b = cvt_pk(o[nd][2] * inv, o[nd][3] * inv);
      const h4 v4 = {a[0], a[1], b[0], b[1]};
      *(h4*)&ctx[(long)qg * EMB + h * DH + nd * 16 + hi * 4] = v4;
    }
  }
}

__device__ __forceinline__ void phaseB_item(
    char* smem, int bid, int tid,
    const _Float16* __restrict__ P, const _Float16* __restrict__ vl,
    const float* __restrict__ Vall, const float* __restrict__ Vtail,
    const _Float16* __restrict__ pO, const float2* __restrict__ ml,
    const int* __restrict__ gmask, const int* __restrict__ qsel,
    const int* __restrict__ qcnt, _Float16* __restrict__ ctx) {
  if (bid < 1024) {
    // rows q<256, gmask==0: per-64-lane-group head; 4 heads per block
    const int q = bid & 255, hg = bid >> 8;
    if (gmask[q] == 1) return;
    const int sub = tid >> 6, l = tid & 63;
    const int hh = hg * 4 + sub;
    float* wgt = (float*)smem;   // [4][256] f32
    const _Float16* Pr = P + ((long)hh * 256 + q) * 256;
    float sv[4];
    bool valid[4];
    float M = -1e30f;
    #pragma unroll
    for (int i = 0; i < 4; ++i) {
      const int k = l + i * 64;
      valid[i] = (k <= q);
      sv[i] = valid[i] ? (float)Pr[k] * 0.015625f : -1e30f;  // (1/8 mean)*(1/8 scale)
      M = fmaxf(M, sv[i]);
    }
    M = fmaxf(M, __shfl_xor(M, 1));
    M = fmaxf(M, __shfl_xor(M, 2));
    M = fmaxf(M, __shfl_xor(M, 4));
    M = fmaxf(M, __shfl_xor(M, 8));
    M = fmaxf(M, __shfl_xor(M, 16));
    M = fmaxf(M, __shfl_xor(M, 32));
    M = fmaxf(M, 0.f);   // 1792 zero-pad entries participate
    float ps = 0.f;
    #pragma unroll
    for (int i = 0; i < 4; ++i) {
      const float e = valid[i] ? __expf(sv[i] - M) : 0.f;
      wgt[sub * 256 + l + i * 64] = e;
      ps += e;
    }
    ps += __shfl_xor(ps, 1);
    ps += __shfl_xor(ps, 2);
    ps += __shfl_xor(ps, 4);
    ps += __shfl_xor(ps, 8);
    ps += __shfl_xor(ps, 16);
    ps += __shfl_xor(ps, 32);
    const float em = __expf(-M);
    const float denom = ps + 1792.f * em;
    const int d = l;
    float acc = em * Vtail[hh * 64 + d];
    const _Float16* vb = vl + (long)hh * 128 * 1024 + d;
    for (int k = 0; k <= q; ++k)
      acc += wgt[sub * 256 + k] * (float)vb[(long)(k >> 4) * 1024 + (k & 15) * 64];
    ctx[(long)q * EMB + hh * DH + d] = (_Float16)(acc / denom);
    __syncthreads();
    return;
  }
  if (bid < 1536) {
    // split-K combine for chunked compacted tiles
    const int b2 = bid - 1024;              // 0..511
    const int h = b2 & 15, tile = b2 >> 4;  // tile 0..31
    int cnt = qcnt[0];
    cnt = cnt < 1 ? 1 : (cnt > 2048 ? 2048 : cnt);   // rocprof-replay poison guard
    if (tile * 64 >= cnt) return;
    const int L = (qsel[min(tile * 64 + 63, cnt - 1)] & 2047) + 1;
    if (((L + 63) >> 6) <= 16) return;      // direct-written by flash
    const int q = tid >> 2, ds = (tid & 3) * 16;
    const int row = tile * 64 + q;
    if (row >= cnt) return;
    const int sg = qsel[row] & 2047;
    const int slot0 = (h * 32 + tile) * 2, slot1 = slot0 + 1;
    const float2 ml0 = ml[slot0 * 64 + q];
    const float2 ml1 = ml[slot1 * 64 + q];
    const float M = fmaxf(ml0.x, ml1.x);
    const float w0 = exp2f(ml0.x - M), w1 = exp2f(ml1.x - M);
    const float inv = 1.f / (w0 * ml0.y + w1 * ml1.y);
    const h8 a0 = *(const h8*)&pO[(long)slot0 * 4096 + q * 64 + ds];
    const h8 a1 = *(const h8*)&pO[(long)slot0 * 4096 + q * 64 + ds + 8];
    const h8 b0 = *(const h8*)&pO[(long)slot1 * 4096 + q * 64 + ds];
    const h8 b1 = *(const h8*)&pO[(long)slot1 * 4096 + q * 64 + ds + 8];
    h8 r0, r1;
    #pragma unroll
    for (int j = 0; j < 8; ++j) {
      r0[j] = (_Float16)((w0 * (float)a0[j] + w1 * (float)b0[j]) * inv);
      r1[j] = (_Float16)((w0 * (float)a1[j] + w1 * (float)b1[j]) * inv);
    }
    *(h8*)&ctx[(long)sg * EMB + h * DH + ds] = r0;
    *(h8*)&ctx[(long)sg * EMB + h * DH + ds + 8] = r1;
    return;
  }
  // tail: rows q>=256, gmask==0 -> Vall/2048 (8 f16 per thread)
  const int gid = (bid - 1536) * 256 + tid;   // x8 elements
  const int s = 256 + (gid >> 7), e8 = (gid & 127) * 8;
  if (gmask[s] == 0) {
    h8 v;
    #pragma unroll
    for (int j = 0; j < 8; ++j)
      v[j] = (_Float16)(Vall[e8 + j] * (1.f / 2048.f));
    *(h8*)&ctx[(long)s * EMB + e8] = v;
  }
}

__device__ __forceinline__ void phaseC_item(
    char* smem, int item, int tid,
    const _Float16* __restrict__ A, const _Float16* __restrict__ Bt,
    float* __restrict__ C, const float* __restrict__ bias) {
  const int bm = (item >> 4) * 64, bn = (item & 15) * 64;
  _Float16* As = (_Float16*)smem;             // [2][4096]
  _Float16* Bs = (_Float16*)(smem + 16384);   // [2][4096]
  const int w = tid >> 6, l = tid & 63;
  const int lo = l & 15, hi = l >> 4;
  const int srow = tid >> 3;             // 0..31
  const int ssl = (tid & 7) ^ (srow & 7);

#define STG64(b, k0) do {                                                            \
    async_copy16(&A[(long)(bm + srow) * 1024 + (k0) + ssl * 8], &As[(b) * 4096 + (w * 8) * 64]); \
    async_copy16(&A[(long)(bm + 32 + srow) * 1024 + (k0) + ssl * 8],                 \
                 &As[(b) * 4096 + (w * 8 + 32) * 64]);                               \
    async_copy16(&Bt[(long)(bn + srow) * 1024 + (k0) + ssl * 8], &Bs[(b) * 4096 + (w * 8) * 64]); \
    async_copy16(&Bt[(long)(bn + 32 + srow) * 1024 + (k0) + ssl * 8],                \
                 &Bs[(b) * 4096 + (w * 8 + 32) * 64]);                               \
  } while (0)

  const f4 zero = {0.f, 0.f, 0.f, 0.f};
  f4 acc[4];
  #pragma unroll
  for (int n = 0; n < 4; ++n) acc[n] = zero;

  STG64(0, 0);
  __syncthreads();
  int cur = 0;
  for (int k0 = 0; k0 < 1024; k0 += 64) {
    if (k0 + 64 < 1024) STG64(cur ^ 1, k0 + 64);
    #pragma unroll
    for (int kk = 0; kk < 2; ++kk) {
      const int ra = w * 16 + lo;
      const h8 af = *(const h8*)&As[cur * 4096 + ra * 64 + (((kk * 4 + hi) ^ (ra & 7)) * 8)];
      #pragma unroll
      for (int n = 0; n < 4; ++n) {
        const int rb = n * 16 + lo;
        const h8 bff = *(const h8*)&Bs[cur * 4096 + rb * 64 + (((kk * 4 + hi) ^ (rb & 7)) * 8)];
        acc[n] = mfma16(af, bff, acc[n]);
      }
    }
    __syncthreads();
    cur ^= 1;
  }
#undef STG64

  #pragma unroll
  for (int n = 0; n < 4; ++n) {
    const int col = bn + n * 16 + lo;
    const float bv = bias[col];
    const int row0 = bm + w * 16 + hi * 4;
    #pragma unroll
    for (int r = 0; r < 4; ++r)
      C[(long)(row0 + r) * 1024 + col] = acc[n][r] + bv;
  }
}

// ---- cooperative fused tail ----
__global__ __launch_bounds__(256, 3) void tail_kernel(
    const _Float16* Q, const _Float16* Km, const _Float16* Vt,
    const int* qsel, const int* qcnt, _Float16* ctx,
    _Float16* pO, float2* ml, const _Float16* Aq, const _Float16* Ak,
    _Float16* P, const _Float16* vl, float* Vall, float* Vtail,
    const int* gmask, const _Float16* Wpt, float* out, const float* bp) {
  __shared__ alignas(16) char smem[43008];
  cg::grid_group grid = cg::this_grid();
  const int nb = gridDim.x;
  const int tid = threadIdx.x;

  for (int item = blockIdx.x; item < 1104; item += nb)
    phaseA_item(smem, item, tid, Q, Km, Vt, qsel, qcnt, ctx, pO, ml,
                Aq, Ak, P, vl, Vall, Vtail);
  grid.sync();
  for (int item = blockIdx.x; item < 2432; item += nb)
    phaseB_item(smem, item, tid, P, vl, Vall, Vtail, pO, ml, gmask, qsel, qcnt, ctx);
  grid.sync();
  for (int item = blockIdx.x; item < 512; item += nb)
    phaseC_item(smem, item, tid, ctx, Wpt, out, bp);
}

// ---- fallback separate kernels (identical device code) ----
__global__ __launch_bounds__(256) void flashsep_kernel(
    const _Float16* Q, const _Float16* Km, const _Float16* Vt,
    const int* qsel, const int* qcnt, _Float16* ctx,
    _Float16* pO, float2* ml, const _Float16* Aq, const _Float16* Ak,
    _Float16* P, const _Float16* vl, float* Vall, float* Vtail) {
  __shared__ alignas(16) char smem[43008];
  phaseA_item(smem, blockIdx.x, threadIdx.x, Q, Km, Vt, qsel, qcnt, ctx, pO, ml,
              Aq, Ak, P, vl, Vall, Vtail);
}

__global__ __launch_bounds__(256) void localfinsep_kernel(
    const _Float16* P, const _Float16* vl, const float* Vall, const float* Vtail,
    const _Float16* pO, const float2* ml, const int* gmask, const int* qsel,
    const int* qcnt, _Float16* ctx) {
  __shared__ alignas(16) char smem[4096];
  phaseB_item(smem, blockIdx.x, threadIdx.x, P, vl, Vall, Vtail, pO, ml,
              gmask, qsel, qcnt, ctx);
}

__global__ __launch_bounds__(256) void gemm64sep_kernel(
    const _Float16* A, const _Float16* Bt, float* C, const float* bias) {
  __shared__ alignas(16) char smem[32768];
  phaseC_item(smem, blockIdx.x, threadIdx.x, A, Bt, C, bias);
}

// ---------------- launcher ----------------
extern "C" void kernel_launch(void* const* d_in, const int* in_sizes, int n_in,
                              void* d_out, int out_size, void* d_ws, size_t ws_size,
                              hipStream_t stream) {
  const float* x = (const float*)d_in[0];
  const int* gmask = (const int*)d_in[1];
  const float* Wlq = (const float*)d_in[2];
  const float* Wlk = (const float*)d_in[3];
  const float* Wlv = (const float*)d_in[4];
  const float* Wq = (const float*)d_in[5];
  const float* Wk = (const float*)d_in[6];
  const float* Wv = (const float*)d_in[7];
  const float* Wp = (const float*)d_in[8];
  const float* bp = (const float*)d_in[9];
  float* out = (float*)d_out;

  char* ws = (char*)d_ws;
  _Float16* xh = (_Float16*)(ws);                    // [0,4)  prep->gemm256; then pO
  _Float16* Wtb = (_Float16*)(ws + (4u << 20));      // [4,18) prep->gemm256
  _Float16* pO = (_Float16*)(ws);                    // [0,8)  tail phase A->B
  _Float16* ctx = (_Float16*)(ws + (8u << 20));      // [8,12)
  _Float16* P = (_Float16*)(ws + (12u << 20));       // [12,14)
  float* Vall = (float*)(ws + (14u << 20));          // [14,16)
  float* Vtail = (float*)(ws + (14u << 20) + 4096);
  float2* ml = (float2*)(ws + (14u << 20) + 16384);  // 512KB
  _Float16* Wpt = (_Float16*)(ws + (16u << 20));     // [16,18) prep->phase C
  _Float16* Aq = (_Float16*)(ws + (18u << 20));      // [18,22) gemm256->phase A
  _Float16* Ak = (_Float16*)(ws + (22u << 20));      // [22,26)
  _Float16* proj234 = (_Float16*)(ws + (26u << 20)); // [26,38) vl,qg,kg
  _Float16* vl = proj234;                            // [26,30)
  _Float16* qg = (_Float16*)(ws + (30u << 20));      // [30,34)
  _Float16* kg = (_Float16*)(ws + (34u << 20));      // [34,38)
  _Float16* vgT = (_Float16*)(ws + (38u << 20));     // [38,42)
  int* qsel = (int*)(ws + (42u << 20));
  int* qcnt = (int*)(ws + (42u << 20) + 8192);

  prep_kernel<<<9217, 256, 0, stream>>>(x, Wlq, Wlk, Wlv, Wq, Wk, Wv, Wp, xh, Wtb,
                                        gmask, qsel, qcnt);
  gemm256_kernel<<<192, 512, 0, stream>>>(xh, Wtb, Aq, Ak, proj234, vgT);

  // cooperative fused tail, with driver-sanctioned grid and checked fallback
  bool done = false;
  int maxPerCU = 0;
  if (hipOccupancyMaxActiveBlocksPerMultiprocessor(
          &maxPerCU, (const void*)tail_kernel, 256, 0) == hipSuccess &&
      maxPerCU >= 1) {
    int coopGrid = maxPerCU * 256;
    if (coopGrid > 768) coopGrid = 768;
    if (coopGrid >= 256) {
      const _Float16* qgc = qg; const _Float16* kgc = kg; const _Float16* vgTc = vgT;
      const int* qselc = qsel; const int* qcntc = qcnt;
      const _Float16* Aqc = Aq; const _Float16* Akc = Ak; const _Float16* vlc = vl;
      const int* gmaskc = gmask; const _Float16* Wptc = Wpt; const float* bpc = bp;
      void* args[] = {(void*)&qgc, (void*)&kgc, (void*)&vgTc, (void*)&qselc,
                      (void*)&qcntc, (void*)&ctx, (void*)&pO, (void*)&ml,
                      (void*)&Aqc, (void*)&Akc, (void*)&P, (void*)&vlc,
                      (void*)&Vall, (void*)&Vtail, (void*)&gmaskc, (void*)&Wptc,
                      (void*)&out, (void*)&bpc};
      if (hipLaunchCooperativeKernel((void*)tail_kernel, dim3(coopGrid), dim3(256),
                                     args, 0, stream) == hipSuccess)
        done = true;
    }
  }
  if (!done) {
    flashsep_kernel<<<1104, 256, 0, stream>>>(qg, kg, vgT, qsel, qcnt, ctx, pO, ml,
                                              Aq, Ak, P, vl, Vall, Vtail);
    localfinsep_kernel<<<2432, 256, 0, stream>>>(P, vl, Vall, Vtail, pO, ml, gmask,
                                                 qsel, qcnt, ctx);
    gemm64sep_kernel<<<512, 256, 0, stream>>>(ctx, Wpt, out, bp);
  }
}

// Round 15
// 121.968 us; speedup vs baseline: 1.7836x; 1.7836x over previous
//
#include <hip/hip_runtime.h>
#include <hip/hip_bf16.h>

typedef _Float16 h8 __attribute__((ext_vector_type(8)));
typedef _Float16 h4 __attribute__((ext_vector_type(4)));
typedef _Float16 h2 __attribute__((ext_vector_type(2)));
typedef __fp16 fp16x2 __attribute__((ext_vector_type(2)));
typedef float f4 __attribute__((ext_vector_type(4)));

#define S_LEN 2048
#define EMB 1024
#define NH 16
#define DH 64

__device__ __forceinline__ void async_copy16(const void* g, void* l) {
  __builtin_amdgcn_global_load_lds(
      (const __attribute__((address_space(1))) void*)g,
      (__attribute__((address_space(3))) void*)l, 16, 0, 0);
}

__device__ __forceinline__ f4 mfma16(h8 a, h8 b, f4 c) {
  return __builtin_amdgcn_mfma_f32_16x16x32_f16(a, b, c, 0, 0, 0);
}

__device__ __forceinline__ h2 cvt_pk(float a, float b) {
  const fp16x2 r = __builtin_amdgcn_cvt_pkrtz(a, b);
  return __builtin_bit_cast(h2, r);
}

// ------- fused prep: x->f16 cast + 7 weight transposes + gmask compaction scan ----
__global__ __launch_bounds__(256) void prep_kernel(
    const float* __restrict__ x, const float* w0, const float* w1, const float* w2,
    const float* w3, const float* w4, const float* w5, const float* w6,
    _Float16* __restrict__ xh, _Float16* __restrict__ Wtb,
    const int* __restrict__ gmask, int* __restrict__ qsel, int* __restrict__ qcnt) {
  const int bid = blockIdx.x;
  if (bid < 2048) {
    const int i = bid * 256 + threadIdx.x;      // *4 elements
    const float4 v = *(const float4*)&x[(long)i * 4];
    h4 o;
    o.x = (_Float16)v.x; o.y = (_Float16)v.y; o.z = (_Float16)v.z; o.w = (_Float16)v.w;
    *(h4*)&xh[(long)i * 4] = o;
    return;
  }
  if (bid < 9216) {
    const int b2 = bid - 2048;
    const int z = b2 >> 10, rem = b2 & 1023;
    const float* W = w0;
    switch (z) {
      case 1: W = w1; break; case 2: W = w2; break; case 3: W = w3; break;
      case 4: W = w4; break; case 5: W = w5; break; case 6: W = w6; break;
      default: break;
    }
    __shared__ float t[32][33];
    const int bk = (rem & 31) * 32, bn = (rem >> 5) * 32;
    const int tx = threadIdx.x & 31, ty = threadIdx.x >> 5;   // 32 x 8
    #pragma unroll
    for (int i = 0; i < 4; ++i)
      t[ty + i * 8][tx] = W[(long)(bk + ty + i * 8) * 1024 + bn + tx];
    __syncthreads();
    _Float16* o = Wtb + (long)z * 1048576;
    #pragma unroll
    for (int i = 0; i < 4; ++i)
      o[(long)(bn + ty + i * 8) * 1024 + bk + tx] = (_Float16)t[tx][ty + i * 8];
    return;
  }
  // gmask==1 compaction scan (single block)
  const int t = threadIdx.x;
  int m8[8], cnt8 = 0;
  #pragma unroll
  for (int j = 0; j < 8; ++j) {
    m8[j] = gmask[t * 8 + j];
    cnt8 += (m8[j] == 1);
  }
  __shared__ int sc[256];
  sc[t] = cnt8;
  __syncthreads();
  for (int off = 1; off < 256; off <<= 1) {
    const int v = (t >= off) ? sc[t - off] : 0;
    __syncthreads();
    sc[t] += v;
    __syncthreads();
  }
  int base = sc[t] - cnt8;
  #pragma unroll
  for (int j = 0; j < 8; ++j)
    if (m8[j] == 1) qsel[base++] = t * 8 + j;
  if (t == 255) qcnt[0] = sc[255];
}

// ---------------- 8-phase 256x256 deep-pipelined GEMM (projection) ----------------
__global__ __launch_bounds__(512, 2) void gemm256_kernel(
    const _Float16* __restrict__ A, const _Float16* __restrict__ Bt,
    _Float16* __restrict__ Aq, _Float16* __restrict__ Ak,
    _Float16* __restrict__ proj234, _Float16* __restrict__ vgT) {
  const int bid = blockIdx.x;                 // 192 blocks
  const int bxx = (bid >> 3) & 7;             // m-block 0..7
  const int byy = (bid & 7) * 3 + (bid >> 6); // n-block 0..23, XCD-pinned
  const int bm = bxx * 256, bn = byy * 256;

  __shared__ alignas(16) _Float16 As[2][2][8192];
  __shared__ alignas(16) _Float16 Bs[2][2][8192];

  const int tid = threadIdx.x;
  const int w = tid >> 6, l = tid & 63;
  const int lo = l & 15, hi = l >> 4;
  const int wm = w >> 2, wn = w & 3;
  const int srow = tid >> 3;                  // 0..63
  const int kseg = (tid & 7) ^ (srow & 7);    // source-preswizzled k-seg

  const _Float16* Bb = Bt + (long)(byy >> 2) * 1048576 + (long)(bn & 1023) * 1024;

#define STG_A(db, half, tt) do {                                                     \
    const int t_ = (tt) < 15 ? (tt) : 15;                                            \
    const _Float16* s_ = A + (long)(bm + (half) * 128 + srow) * 1024 + t_ * 64 + kseg * 8; \
    async_copy16(s_, &As[db][half][w * 512]);                                        \
    async_copy16(s_ + 65536, &As[db][half][4096 + w * 512]);                         \
  } while (0)
#define STG_B(db, half, tt) do {                                                     \
    const int t_ = (tt) < 15 ? (tt) : 15;                                            \
    const _Float16* s_ = Bb + (long)((half) * 128 + srow) * 1024 + t_ * 64 + kseg * 8; \
    async_copy16(s_, &Bs[db][half][w * 512]);                                        \
    async_copy16(s_ + 65536, &Bs[db][half][4096 + w * 512]);                         \
  } while (0)
#define LDA(db, mg) do { _Pragma("unroll")                                           \
    for (int fr = 0; fr < 4; ++fr) {                                                 \
      const int rr = wm * 64 + fr * 16 + lo;                                         \
      _Pragma("unroll") for (int kk = 0; kk < 2; ++kk)                               \
        af[fr][kk] = *(const h8*)&As[db][mg][rr * 64 + (((kk * 4 + hi) ^ (rr & 7)) * 8)]; \
    } } while (0)
#define LDB(db, ng) do { _Pragma("unroll")                                           \
    for (int fc = 0; fc < 2; ++fc) {                                                 \
      const int rr = wn * 32 + fc * 16 + lo;                                         \
      _Pragma("unroll") for (int kk = 0; kk < 2; ++kk)                               \
        bf[ng][fc][kk] = *(const h8*)&Bs[db][ng][rr * 64 + (((kk * 4 + hi) ^ (rr & 7)) * 8)]; \
    } } while (0)
#define MFMA_PH(mg, ng) do {                                                         \
    __builtin_amdgcn_s_setprio(1);                                                   \
    _Pragma("unroll") for (int fr = 0; fr < 4; ++fr)                                 \
      _Pragma("unroll") for (int fc = 0; fc < 2; ++fc) {                             \
        acc[mg][fr][ng][fc] = mfma16(af[fr][0], bf[ng][fc][0], acc[mg][fr][ng][fc]); \
        acc[mg][fr][ng][fc] = mfma16(af[fr][1], bf[ng][fc][1], acc[mg][fr][ng][fc]); \
      }                                                                              \
    __builtin_amdgcn_s_setprio(0);                                                   \
  } while (0)
#define BARR do { asm volatile("" ::: "memory"); __builtin_amdgcn_s_barrier();       \
                  asm volatile("" ::: "memory"); } while (0)
#define VM8 asm volatile("s_waitcnt vmcnt(8)" ::: "memory")

  const f4 zero = {0.f, 0.f, 0.f, 0.f};
  f4 acc[2][4][2][2];
  #pragma unroll
  for (int a_ = 0; a_ < 2; ++a_)
    #pragma unroll
    for (int b_ = 0; b_ < 4; ++b_)
      #pragma unroll
      for (int c_ = 0; c_ < 2; ++c_)
        #pragma unroll
        for (int d_ = 0; d_ < 2; ++d_) acc[a_][b_][c_][d_] = zero;
  h8 af[4][2];
  h8 bf[2][2][2];

  STG_A(0, 0, 0); STG_B(0, 0, 0); STG_A(0, 1, 0); STG_B(0, 1, 0);
  STG_A(1, 0, 1); STG_B(1, 0, 1); STG_A(1, 1, 1);
  asm volatile("s_waitcnt vmcnt(4)" ::: "memory");   // covers t0 A0,B0,A1,B1 + t1.A0
  BARR;

  for (int i = 0; i < 8; ++i) {
    const int t2 = 2 * i + 2, t3 = 2 * i + 3;
    LDA(0, 0); LDB(0, 0); STG_B(1, 1, 2 * i + 1); MFMA_PH(0, 0); VM8; BARR;
    LDB(0, 1); STG_A(0, 0, t2); MFMA_PH(0, 1); BARR;
    LDA(0, 1); STG_B(0, 0, t2); MFMA_PH(1, 0); BARR;
    STG_A(0, 1, t2); MFMA_PH(1, 1); VM8; BARR;
    LDA(1, 0); LDB(1, 0); STG_B(0, 1, t2); MFMA_PH(0, 0); VM8; BARR;
    LDB(1, 1); STG_A(1, 0, t3); MFMA_PH(0, 1); BARR;
    LDA(1, 1); STG_B(1, 0, t3); MFMA_PH(1, 0); BARR;
    STG_A(1, 1, t3); MFMA_PH(1, 1); VM8; BARR;
  }

  // epilogue: per-slab consumer layout
  const int slabv = byy >> 2;
  #pragma unroll
  for (int mg = 0; mg < 2; ++mg)
    #pragma unroll
    for (int fr = 0; fr < 4; ++fr) {
      const int row0 = bm + mg * 128 + wm * 64 + fr * 16 + hi * 4;
      #pragma unroll
      for (int ng = 0; ng < 2; ++ng)
        #pragma unroll
        for (int fc = 0; fc < 2; ++fc) {
          const int colg = bn + ng * 128 + wn * 32 + fc * 16 + lo;
          const int e = colg & 1023;
          if (slabv <= 1) {
            _Float16* dst = (slabv == 0) ? Aq : Ak;
            #pragma unroll
            for (int r = 0; r < 4; ++r) {
              const int s = row0 + r;
              const long off = (long)(((s >> 7) * 256 + (s & 15) * 16 + (e >> 6))) * 512
                               + ((s >> 4) & 7) * 64 + (e & 63);
              dst[off] = (_Float16)acc[mg][fr][ng][fc][r];
            }
          } else if (slabv == 5) {
            const h2 a = cvt_pk(acc[mg][fr][ng][fc][0], acc[mg][fr][ng][fc][1]);
            const h2 b = cvt_pk(acc[mg][fr][ng][fc][2], acc[mg][fr][ng][fc][3]);
            const h4 v4 = {a[0], a[1], b[0], b[1]};
            *(h4*)&vgT[(long)e * 2048 + row0] = v4;
          } else {
            _Float16* cp = proj234 + (long)(slabv - 2) * 2097152 + (long)row0 * 1024 + e;
            #pragma unroll
            for (int r = 0; r < 4; ++r)
              cp[(long)r * 1024] = (_Float16)acc[mg][fr][ng][fc][r];
          }
        }
    }
#undef STG_A
#undef STG_B
#undef LDA
#undef LDB
#undef MFMA_PH
#undef BARR
#undef VM8
}

// ------- mega flash: compacted split-K flash (V direct-from-L2) + P-gemm + Vsum ---
// grid 1296: [0,1024) flash | [1024,1280) P-gemm 64^2 | [1280,1296) Vsum
// Flash LDS: K double-buffered (16KB) + Ps (10KB) = 26KB -> 6 blocks/CU.
// V fragments load straight from vgT (XCD-pinned, L2-resident) into registers.
__global__ __launch_bounds__(256) void flash_kernel(
    const _Float16* __restrict__ Q, const _Float16* __restrict__ Km,
    const _Float16* __restrict__ Vt, const int* __restrict__ qsel,
    const int* __restrict__ qcnt, _Float16* __restrict__ ctx,
    _Float16* __restrict__ pO, float2* __restrict__ ml,
    const _Float16* __restrict__ Aq, const _Float16* __restrict__ Ak,
    _Float16* __restrict__ P, const _Float16* __restrict__ vl,
    float* __restrict__ Vall, float* __restrict__ Vtail) {
  __shared__ alignas(16) char smem[26624];   // union: flash 26.6KB | P-gemm 16KB | Vsum 2KB
  const int bx = blockIdx.x;
  const int tid = threadIdx.x;

  if (bx >= 1280) {
    // ---- V column sums per head ----
    const int hh = bx - 1280;
    const int d = tid & 63, g = tid >> 6;
    float sall = 0.f, shead = 0.f;
    for (int i = 0; i < 32; ++i) {
      const int ro = g * 32 + i;  // 0..127
      const _Float16* base = vl + (long)(hh * 128 + ro) * 1024 + d;
      #pragma unroll
      for (int j = 0; j < 16; ++j) {
        const float v = (float)base[j * 64];
        sall += v;
        if (ro < 16) shead += v;
      }
    }
    float* sA = (float*)smem;            // [4][64]
    float* sH = (float*)(smem + 1024);   // [4][64]
    sA[g * 64 + d] = sall; sH[g * 64 + d] = shead;
    __syncthreads();
    if (g == 0) {
      const float a = sA[d] + sA[64 + d] + sA[128 + d] + sA[192 + d];
      const float hsum = sH[d] + sH[64 + d] + sH[128 + d] + sH[192 + d];
      Vall[hh * 64 + d] = a;
      Vtail[hh * 64 + d] = a - hsum;
    }
    return;
  }

  if (bx >= 1024) {
    // ---- P-gemm: P[h] = Aq[h] * Ak[h]^T, 64^2 tiles, K=512, single-buffered ----
    const int b = bx - 1024;                 // 0..255
    const int hh = b >> 4, sub = b & 15;
    const int bm = (sub >> 2) * 64, bn = (sub & 3) * 64;
    const _Float16* Ab = Aq + (long)hh * 131072;
    const _Float16* Bb = Ak + (long)hh * 131072;
    _Float16* As = (_Float16*)smem;            // [64][64]
    _Float16* Bs = (_Float16*)(smem + 8192);   // [64][64]
    const int w = tid >> 6, l = tid & 63;
    const int lo = l & 15, hi = l >> 4;
    const int srow = tid >> 3;                 // 0..31
    const int ssl = (tid & 7) ^ (srow & 7);

    const f4 zero = {0.f, 0.f, 0.f, 0.f};
    f4 acc[4];
    #pragma unroll
    for (int n = 0; n < 4; ++n) acc[n] = zero;

    for (int k0 = 0; k0 < 512; k0 += 64) {
      async_copy16(&Ab[(long)(bm + srow) * 512 + k0 + ssl * 8], &As[(w * 8) * 64]);
      async_copy16(&Ab[(long)(bm + 32 + srow) * 512 + k0 + ssl * 8], &As[(w * 8 + 32) * 64]);
      async_copy16(&Bb[(long)(bn + srow) * 512 + k0 + ssl * 8], &Bs[(w * 8) * 64]);
      async_copy16(&Bb[(long)(bn + 32 + srow) * 512 + k0 + ssl * 8], &Bs[(w * 8 + 32) * 64]);
      __syncthreads();
      #pragma unroll
      for (int kk = 0; kk < 2; ++kk) {
        const int ra = w * 16 + lo;
        const h8 af = *(const h8*)&As[ra * 64 + (((kk * 4 + hi) ^ (ra & 7)) * 8)];
        #pragma unroll
        for (int n = 0; n < 4; ++n) {
          const int rb = n * 16 + lo;
          const h8 bff = *(const h8*)&Bs[rb * 64 + (((kk * 4 + hi) ^ (rb & 7)) * 8)];
          acc[n] = mfma16(af, bff, acc[n]);
        }
      }
      __syncthreads();
    }
    #pragma unroll
    for (int n = 0; n < 4; ++n) {
      const int col = bn + n * 16 + lo;
      const int row0 = bm + w * 16 + hi * 4;
      #pragma unroll
      for (int r = 0; r < 4; ++r)
        P[(long)hh * 65536 + (long)(row0 + r) * 256 + col] = (_Float16)acc[n][r];
    }
    return;
  }

  // ---- flash ----
  const int h = bx & 15;
  const int v = bx >> 4;               // 0..63
  const int tile = 31 - (v >> 1);      // heavy-first
  const int chunk = v & 1;
  int cnt = qcnt[0];
  cnt = cnt < 1 ? 1 : (cnt > 2048 ? 2048 : cnt);   // rocprof-replay poison guard
  if (tile * 64 >= cnt) return;
  const int L = (qsel[min(tile * 64 + 63, cnt - 1)] & 2047) + 1;
  const int ntot = (L + 63) >> 6;
  const bool chunked = (ntot > 16);
  if (!chunked && chunk) return;
  const int nsplit = chunked ? ((ntot + 1) >> 1) : ntot;
  const int t0 = chunk ? nsplit : 0;
  const int t1 = chunk ? ntot : nsplit;

  const int w = tid >> 6, l = tid & 63;
  const int lo = l & 15, hi = l >> 4;
  const int row = tile * 64 + w * 16 + lo;
  const int qg = qsel[min(row, cnt - 1)] & 2047;   // orig seq position

  _Float16* KsB = (_Float16*)smem;                       // [2][4096]
  _Float16* ps = (_Float16*)(smem + 16384) + w * 1280;   // [16 q][80]

  const int rl = tid >> 3;              // 0..31
  const int ssl = (tid & 7) ^ (rl & 7); // source-preswizzled k-seg

#define STAGE(b, t)                                                                   \
  do {                                                                                \
    async_copy16(&Km[(long)((t) * 64 + rl) * EMB + h * DH + ssl * 8],                 \
                 &KsB[(b) * 4096 + (w * 8) * 64]);                                    \
    async_copy16(&Km[(long)((t) * 64 + 32 + rl) * EMB + h * DH + ssl * 8],            \
                 &KsB[(b) * 4096 + (w * 8 + 32) * 64]);                               \
  } while (0)

  h8 qf[2];
  #pragma unroll
  for (int kk = 0; kk < 2; ++kk)
    qf[kk] = *(const h8*)&Q[(long)qg * EMB + h * DH + kk * 32 + hi * 8];

  const f4 zero = {0.f, 0.f, 0.f, 0.f};
  f4 o[4];
  #pragma unroll
  for (int nd = 0; nd < 4; ++nd) o[nd] = zero;
  float mr = -1e30f, lr = 0.f;
  const float SC = 0.125f * 1.44269504f;   // scale folded into log2 domain

  STAGE(0, t0);
  __syncthreads();
  int cur = 0;

  for (int t = t0; t < t1; ++t) {
    if (t + 1 < t1) STAGE(cur ^ 1, t + 1);   // prefetch next K tile (async)

    // V fragments: direct from L2-resident vgT (issued early, used in PV)
    h8 vf[4][2];
    #pragma unroll
    for (int nd = 0; nd < 4; ++nd)
      #pragma unroll
      for (int kk = 0; kk < 2; ++kk)
        vf[nd][kk] = *(const h8*)&Vt[(long)(h * DH + nd * 16 + lo) * S_LEN
                                     + t * 64 + kk * 32 + hi * 8];

    const _Float16* ks = KsB + cur * 4096;

    // ---- QK^T (S^T = K x Q) ----
    __builtin_amdgcn_s_setprio(1);
    f4 s[4];
    #pragma unroll
    for (int n = 0; n < 4; ++n) {
      s[n] = zero;
      #pragma unroll
      for (int kk = 0; kk < 2; ++kk) {
        const int r = n * 16 + lo;
        const h8 kf = *(const h8*)&ks[r * 64 + (((kk * 4 + hi) ^ (lo & 7)) * 8)];
        s[n] = mfma16(kf, qf[kk], s[n]);
      }
    }
    __builtin_amdgcn_s_setprio(0);

    // ---- online softmax (log2 domain), q lane-local, causal vs qg ----
    float sv[16];
    float tm = -1e30f;
    #pragma unroll
    for (int n = 0; n < 4; ++n)
      #pragma unroll
      for (int r = 0; r < 4; ++r) {
        float vv = s[n][r] * SC;
        if ((t * 64 + n * 16 + hi * 4 + r) > qg) vv = -1e30f;
        sv[n * 4 + r] = vv;
        tm = fmaxf(tm, vv);
      }
    tm = fmaxf(tm, __shfl_xor(tm, 16));
    tm = fmaxf(tm, __shfl_xor(tm, 32));
    const float mn = fmaxf(mr, tm);
    const float c = exp2f(mr - mn);
    mr = mn;
    float psum = 0.f;
    #pragma unroll
    for (int i = 0; i < 16; ++i) {
      sv[i] = exp2f(sv[i] - mr);
      psum += sv[i];
    }
    psum += __shfl_xor(psum, 16);
    psum += __shfl_xor(psum, 32);
    lr = lr * c + psum;

    // ---- pack P^T -> ps[q][key] (row stride 80, XOR-swizzled 16B segs) ----
    #pragma unroll
    for (int n = 0; n < 4; ++n) {
      const int seg = (2 * n + (hi >> 1)) ^ (lo & 7);
      const int base = lo * 80 + seg * 8 + (hi & 1) * 4;
      *(h2*)&ps[base] = cvt_pk(sv[n * 4 + 0], sv[n * 4 + 1]);
      *(h2*)&ps[base + 2] = cvt_pk(sv[n * 4 + 2], sv[n * 4 + 3]);
    }
    h8 pb[2];
    #pragma unroll
    for (int kk = 0; kk < 2; ++kk)
      pb[kk] = *(const h8*)&ps[lo * 80 + (((kk * 4 + hi) ^ (lo & 7)) * 8)];

    // ---- PV: O^T[d][q] += V^T x P (V from registers) ----
    __builtin_amdgcn_s_setprio(1);
    #pragma unroll
    for (int nd = 0; nd < 4; ++nd) {
      #pragma unroll
      for (int r = 0; r < 4; ++r) o[nd][r] *= c;
      #pragma unroll
      for (int kk = 0; kk < 2; ++kk)
        o[nd] = mfma16(vf[nd][kk], pb[kk], o[nd]);
    }
    __builtin_amdgcn_s_setprio(0);

    __syncthreads();   // drains K prefetch + guards Ks reuse
    cur ^= 1;
  }
#undef STAGE

  if (chunked) {
    const int slot = (h * 32 + tile) * 2 + chunk;
    _Float16* po = pO + (long)slot * 4096 + (w * 16 + lo) * 64;
    #pragma unroll
    for (int nd = 0; nd < 4; ++nd) {
      const h2 a = cvt_pk(o[nd][0], o[nd][1]);
      const h2 b = cvt_pk(o[nd][2], o[nd][3]);
      const h4 v4 = {a[0], a[1], b[0], b[1]};
      *(h4*)&po[nd * 16 + hi * 4] = v4;
    }
    if (hi == 0) ml[slot * 64 + w * 16 + lo] = make_float2(mr, lr);
  } else if (row < cnt) {
    const float inv = 1.f / lr;
    #pragma unroll
    for (int nd = 0; nd < 4; ++nd) {
      const h2 a = cvt_pk(o[nd][0] * inv, o[nd][1] * inv);
      const h2 b = cvt_pk(o[nd][2] * inv, o[nd][3] * inv);
      const h4 v4 = {a[0], a[1], b[0], b[1]};
      *(h4*)&ctx[(long)qg * EMB + h * DH + nd * 16 + hi * 4] = v4;
    }
  }
}

// ------- fused finish: local softmax rows + split-K combine + uniform tail -------
__global__ __launch_bounds__(256) void localfin_kernel(
    const _Float16* __restrict__ P, const _Float16* __restrict__ vl,
    const float* __restrict__ Vall, const float* __restrict__ Vtail,
    const _Float16* __restrict__ pO, const float2* __restrict__ ml,
    const int* __restrict__ gmask, const int* __restrict__ qsel,
    const int* __restrict__ qcnt, _Float16* __restrict__ ctx) {
  const int bid = blockIdx.x;
  const int tid = threadIdx.x;
  if (bid < 1024) {
    // rows q<256, gmask==0: per-64-lane-group head; 4 heads per block
    const int q = bid & 255, hg = bid >> 8;
    if (gmask[q] == 1) return;
    const int sub = tid >> 6, l = tid & 63;
    const int hh = hg * 4 + sub;
    __shared__ float wgt[4][256];
    const _Float16* Pr = P + ((long)hh * 256 + q) * 256;
    float sv[4];
    bool valid[4];
    float M = -1e30f;
    #pragma unroll
    for (int i = 0; i < 4; ++i) {
      const int k = l + i * 64;
      valid[i] = (k <= q);
      sv[i] = valid[i] ? (float)Pr[k] * 0.015625f : -1e30f;  // (1/8 mean)*(1/8 scale)
      M = fmaxf(M, sv[i]);
    }
    M = fmaxf(M, __shfl_xor(M, 1));
    M = fmaxf(M, __shfl_xor(M, 2));
    M = fmaxf(M, __shfl_xor(M, 4));
    M = fmaxf(M, __shfl_xor(M, 8));
    M = fmaxf(M, __shfl_xor(M, 16));
    M = fmaxf(M, __shfl_xor(M, 32));
    M = fmaxf(M, 0.f);   // 1792 zero-pad entries participate
    float ps = 0.f;
    #pragma unroll
    for (int i = 0; i < 4; ++i) {
      const float e = valid[i] ? __expf(sv[i] - M) : 0.f;
      wgt[sub][l + i * 64] = e;
      ps += e;
    }
    ps += __shfl_xor(ps, 1);
    ps += __shfl_xor(ps, 2);
    ps += __shfl_xor(ps, 4);
    ps += __shfl_xor(ps, 8);
    ps += __shfl_xor(ps, 16);
    ps += __shfl_xor(ps, 32);
    const float em = __expf(-M);
    const float denom = ps + 1792.f * em;
    const int d = l;
    float acc = em * Vtail[hh * 64 + d];
    const _Float16* vb = vl + (long)hh * 128 * 1024 + d;
    for (int k = 0; k <= q; ++k)
      acc += wgt[sub][k] * (float)vb[(long)(k >> 4) * 1024 + (k & 15) * 64];
    ctx[(long)q * EMB + hh * DH + d] = (_Float16)(acc / denom);
    return;
  }
  if (bid < 1536) {
    // split-K combine for chunked compacted tiles
    const int b2 = bid - 1024;              // 0..511
    const int h = b2 & 15, tile = b2 >> 4;  // tile 0..31
    int cnt = qcnt[0];
    cnt = cnt < 1 ? 1 : (cnt > 2048 ? 2048 : cnt);   // rocprof-replay poison guard
    if (tile * 64 >= cnt) return;
    const int L = (qsel[min(tile * 64 + 63, cnt - 1)] & 2047) + 1;
    if (((L + 63) >> 6) <= 16) return;      // direct-written by flash
    const int q = tid >> 2, ds = (tid & 3) * 16;
    const int row = tile * 64 + q;
    if (row >= cnt) return;
    const int sg = qsel[row] & 2047;
    const int slot0 = (h * 32 + tile) * 2, slot1 = slot0 + 1;
    const float2 ml0 = ml[slot0 * 64 + q];
    const float2 ml1 = ml[slot1 * 64 + q];
    const float M = fmaxf(ml0.x, ml1.x);
    const float w0 = exp2f(ml0.x - M), w1 = exp2f(ml1.x - M);
    const float inv = 1.f / (w0 * ml0.y + w1 * ml1.y);
    const h8 a0 = *(const h8*)&pO[(long)slot0 * 4096 + q * 64 + ds];
    const h8 a1 = *(const h8*)&pO[(long)slot0 * 4096 + q * 64 + ds + 8];
    const h8 b0 = *(const h8*)&pO[(long)slot1 * 4096 + q * 64 + ds];
    const h8 b1 = *(const h8*)&pO[(long)slot1 * 4096 + q * 64 + ds + 8];
    h8 r0, r1;
    #pragma unroll
    for (int j = 0; j < 8; ++j) {
      r0[j] = (_Float16)((w0 * (float)a0[j] + w1 * (float)b0[j]) * inv);
      r1[j] = (_Float16)((w0 * (float)a1[j] + w1 * (float)b1[j]) * inv);
    }
    *(h8*)&ctx[(long)sg * EMB + h * DH + ds] = r0;
    *(h8*)&ctx[(long)sg * EMB + h * DH + ds + 8] = r1;
    return;
  }
  // tail: rows q>=256, gmask==0 -> Vall/2048 (8 f16 per thread)
  const int gid = (bid - 1536) * 256 + tid;   // x8 elements
  const int s = 256 + (gid >> 7), e8 = (gid & 127) * 8;
  if (gmask[s] == 0) {
    h8 v;
    #pragma unroll
    for (int j = 0; j < 8; ++j)
      v[j] = (_Float16)(Vall[e8 + j] * (1.f / 2048.f));
    *(h8*)&ctx[(long)s * EMB + e8] = v;
  }
}

// ---------------- final projection: 64x64 tile, double-buffered, 512 blocks -------
__global__ __launch_bounds__(256) void gemm64_kernel(
    const _Float16* __restrict__ A, const _Float16* __restrict__ Bt,
    float* __restrict__ C, const float* __restrict__ bias) {
  const int bm = blockIdx.x * 64, bn = blockIdx.y * 64;
  __shared__ alignas(16) _Float16 As[2][4096];
  __shared__ alignas(16) _Float16 Bs[2][4096];
  const int tid = threadIdx.x;
  const int w = tid >> 6, l = tid & 63;
  const int lo = l & 15, hi = l >> 4;
  const int srow = tid >> 3;             // 0..31
  const int ssl = (tid & 7) ^ (srow & 7);

#define STG64(b, k0) do {                                                            \
    async_copy16(&A[(long)(bm + srow) * 1024 + (k0) + ssl * 8], &As[b][(w * 8) * 64]); \
    async_copy16(&A[(long)(bm + 32 + srow) * 1024 + (k0) + ssl * 8],                 \
                 &As[b][(w * 8 + 32) * 64]);                                         \
    async_copy16(&Bt[(long)(bn + srow) * 1024 + (k0) + ssl * 8], &Bs[b][(w * 8) * 64]); \
    async_copy16(&Bt[(long)(bn + 32 + srow) * 1024 + (k0) + ssl * 8],                \
                 &Bs[b][(w * 8 + 32) * 64]);                                         \
  } while (0)

  const f4 zero = {0.f, 0.f, 0.f, 0.f};
  f4 acc[4];
  #pragma unroll
  for (int n = 0; n < 4; ++n) acc[n] = zero;

  STG64(0, 0);
  __syncthreads();
  int cur = 0;
  for (int k0 = 0; k0 < 1024; k0 += 64) {
    if (k0 + 64 < 1024) STG64(cur ^ 1, k0 + 64);
    #pragma unroll
    for (int kk = 0; kk < 2; ++kk) {
      const int ra = w * 16 + lo;
      const h8 af = *(const h8*)&As[cur][ra * 64 + (((kk * 4 + hi) ^ (ra & 7)) * 8)];
      #pragma unroll
      for (int n = 0; n < 4; ++n) {
        const int rb = n * 16 + lo;
        const h8 bff = *(const h8*)&Bs[cur][rb * 64 + (((kk * 4 + hi) ^ (rb & 7)) * 8)];
        acc[n] = mfma16(af, bff, acc[n]);
      }
    }
    __syncthreads();
    cur ^= 1;
  }
#undef STG64

  #pragma unroll
  for (int n = 0; n < 4; ++n) {
    const int col = bn + n * 16 + lo;
    const float bv = bias[col];
    const int row0 = bm + w * 16 + hi * 4;
    #pragma unroll
    for (int r = 0; r < 4; ++r)
      C[(long)(row0 + r) * 1024 + col] = acc[n][r] + bv;
  }
}

// ---------------- launcher ----------------
extern "C" void kernel_launch(void* const* d_in, const int* in_sizes, int n_in,
                              void* d_out, int out_size, void* d_ws, size_t ws_size,
                              hipStream_t stream) {
  const float* x = (const float*)d_in[0];
  const int* gmask = (const int*)d_in[1];
  const float* Wlq = (const float*)d_in[2];
  const float* Wlk = (const float*)d_in[3];
  const float* Wlv = (const float*)d_in[4];
  const float* Wq = (const float*)d_in[5];
  const float* Wk = (const float*)d_in[6];
  const float* Wv = (const float*)d_in[7];
  const float* Wp = (const float*)d_in[8];
  const float* bp = (const float*)d_in[9];
  float* out = (float*)d_out;

  char* ws = (char*)d_ws;
  _Float16* xh = (_Float16*)(ws);                    // [0,4)  prep->gemm256; then pO
  _Float16* Wtb = (_Float16*)(ws + (4u << 20));      // [4,18) prep->gemm256
  _Float16* pO = (_Float16*)(ws);                    // [0,8)  flash->localfin
  _Float16* ctx = (_Float16*)(ws + (8u << 20));      // [8,12)
  _Float16* P = (_Float16*)(ws + (12u << 20));       // [12,14)
  float* Vall = (float*)(ws + (14u << 20));          // [14,16)
  float* Vtail = (float*)(ws + (14u << 20) + 4096);
  float2* ml = (float2*)(ws + (14u << 20) + 16384);  // 512KB
  _Float16* Wpt = (_Float16*)(ws + (16u << 20));     // [16,18) prep->gemm64
  _Float16* Aq = (_Float16*)(ws + (18u << 20));      // [18,22) gemm256->flash
  _Float16* Ak = (_Float16*)(ws + (22u << 20));      // [22,26)
  _Float16* proj234 = (_Float16*)(ws + (26u << 20)); // [26,38) vl,qg,kg
  _Float16* vl = proj234;                            // [26,30)
  _Float16* qg = (_Float16*)(ws + (30u << 20));      // [30,34)
  _Float16* kg = (_Float16*)(ws + (34u << 20));      // [34,38)
  _Float16* vgT = (_Float16*)(ws + (38u << 20));     // [38,42)
  int* qsel = (int*)(ws + (42u << 20));
  int* qcnt = (int*)(ws + (42u << 20) + 8192);

  prep_kernel<<<9217, 256, 0, stream>>>(x, Wlq, Wlk, Wlv, Wq, Wk, Wv, Wp, xh, Wtb,
                                        gmask, qsel, qcnt);
  gemm256_kernel<<<192, 512, 0, stream>>>(xh, Wtb, Aq, Ak, proj234, vgT);
  flash_kernel<<<1296, 256, 0, stream>>>(qg, kg, vgT, qsel, qcnt, ctx, pO, ml,
                                         Aq, Ak, P, vl, Vall, Vtail);
  localfin_kernel<<<2432, 256, 0, stream>>>(P, vl, Vall, Vtail, pO, ml, gmask,
                                            qsel, qcnt, ctx);
  gemm64_kernel<<<dim3(32, 16), 256, 0, stream>>>(ctx, Wpt, out, bp);
}

// Round 16
// 115.453 us; speedup vs baseline: 1.8842x; 1.0564x over previous
//
#include <hip/hip_runtime.h>
#include <hip/hip_bf16.h>

typedef _Float16 h8 __attribute__((ext_vector_type(8)));
typedef _Float16 h4 __attribute__((ext_vector_type(4)));
typedef _Float16 h2 __attribute__((ext_vector_type(2)));
typedef __fp16 fp16x2 __attribute__((ext_vector_type(2)));
typedef float f4 __attribute__((ext_vector_type(4)));

#define S_LEN 2048
#define EMB 1024
#define NH 16
#define DH 64

__device__ __forceinline__ void async_copy16(const void* g, void* l) {
  __builtin_amdgcn_global_load_lds(
      (const __attribute__((address_space(1))) void*)g,
      (__attribute__((address_space(3))) void*)l, 16, 0, 0);
}

__device__ __forceinline__ f4 mfma16(h8 a, h8 b, f4 c) {
  return __builtin_amdgcn_mfma_f32_16x16x32_f16(a, b, c, 0, 0, 0);
}

__device__ __forceinline__ h2 cvt_pk(float a, float b) {
  const fp16x2 r = __builtin_amdgcn_cvt_pkrtz(a, b);
  return __builtin_bit_cast(h2, r);
}

// ------- fused prep: x->f16 cast + 7 weight transposes + gmask compaction scan ----
__global__ __launch_bounds__(256) void prep_kernel(
    const float* __restrict__ x, const float* w0, const float* w1, const float* w2,
    const float* w3, const float* w4, const float* w5, const float* w6,
    _Float16* __restrict__ xh, _Float16* __restrict__ Wtb,
    const int* __restrict__ gmask, int* __restrict__ qsel, int* __restrict__ qcnt) {
  const int bid = blockIdx.x;
  if (bid < 2048) {
    const int i = bid * 256 + threadIdx.x;      // *4 elements
    const float4 v = *(const float4*)&x[(long)i * 4];
    h4 o;
    o.x = (_Float16)v.x; o.y = (_Float16)v.y; o.z = (_Float16)v.z; o.w = (_Float16)v.w;
    *(h4*)&xh[(long)i * 4] = o;
    return;
  }
  if (bid < 9216) {
    const int b2 = bid - 2048;
    const int z = b2 >> 10, rem = b2 & 1023;
    const float* W = w0;
    switch (z) {
      case 1: W = w1; break; case 2: W = w2; break; case 3: W = w3; break;
      case 4: W = w4; break; case 5: W = w5; break; case 6: W = w6; break;
      default: break;
    }
    __shared__ float t[32][33];
    const int bk = (rem & 31) * 32, bn = (rem >> 5) * 32;
    const int tx = threadIdx.x & 31, ty = threadIdx.x >> 5;   // 32 x 8
    #pragma unroll
    for (int i = 0; i < 4; ++i)
      t[ty + i * 8][tx] = W[(long)(bk + ty + i * 8) * 1024 + bn + tx];
    __syncthreads();
    _Float16* o = Wtb + (long)z * 1048576;
    #pragma unroll
    for (int i = 0; i < 4; ++i)
      o[(long)(bn + ty + i * 8) * 1024 + bk + tx] = (_Float16)t[tx][ty + i * 8];
    return;
  }
  // gmask==1 compaction scan (single block)
  const int t = threadIdx.x;
  int m8[8], cnt8 = 0;
  #pragma unroll
  for (int j = 0; j < 8; ++j) {
    m8[j] = gmask[t * 8 + j];
    cnt8 += (m8[j] == 1);
  }
  __shared__ int sc[256];
  sc[t] = cnt8;
  __syncthreads();
  for (int off = 1; off < 256; off <<= 1) {
    const int v = (t >= off) ? sc[t - off] : 0;
    __syncthreads();
    sc[t] += v;
    __syncthreads();
  }
  int base = sc[t] - cnt8;
  #pragma unroll
  for (int j = 0; j < 8; ++j)
    if (m8[j] == 1) qsel[base++] = t * 8 + j;
  if (t == 255) qcnt[0] = sc[255];
}

// ---------------- 8-phase 256x256 deep-pipelined GEMM (projection) ----------------
__global__ __launch_bounds__(512, 2) void gemm256_kernel(
    const _Float16* __restrict__ A, const _Float16* __restrict__ Bt,
    _Float16* __restrict__ Aq, _Float16* __restrict__ Ak,
    _Float16* __restrict__ proj234, _Float16* __restrict__ vgT) {
  const int bid = blockIdx.x;                 // 192 blocks
  const int bxx = (bid >> 3) & 7;             // m-block 0..7
  const int byy = (bid & 7) * 3 + (bid >> 6); // n-block 0..23, XCD-pinned
  const int bm = bxx * 256, bn = byy * 256;

  __shared__ alignas(16) _Float16 As[2][2][8192];
  __shared__ alignas(16) _Float16 Bs[2][2][8192];

  const int tid = threadIdx.x;
  const int w = tid >> 6, l = tid & 63;
  const int lo = l & 15, hi = l >> 4;
  const int wm = w >> 2, wn = w & 3;
  const int srow = tid >> 3;                  // 0..63
  const int kseg = (tid & 7) ^ (srow & 7);    // source-preswizzled k-seg

  const _Float16* Bb = Bt + (long)(byy >> 2) * 1048576 + (long)(bn & 1023) * 1024;

#define STG_A(db, half, tt) do {                                                     \
    const int t_ = (tt) < 15 ? (tt) : 15;                                            \
    const _Float16* s_ = A + (long)(bm + (half) * 128 + srow) * 1024 + t_ * 64 + kseg * 8; \
    async_copy16(s_, &As[db][half][w * 512]);                                        \
    async_copy16(s_ + 65536, &As[db][half][4096 + w * 512]);                         \
  } while (0)
#define STG_B(db, half, tt) do {                                                     \
    const int t_ = (tt) < 15 ? (tt) : 15;                                            \
    const _Float16* s_ = Bb + (long)((half) * 128 + srow) * 1024 + t_ * 64 + kseg * 8; \
    async_copy16(s_, &Bs[db][half][w * 512]);                                        \
    async_copy16(s_ + 65536, &Bs[db][half][4096 + w * 512]);                         \
  } while (0)
#define LDA(db, mg) do { _Pragma("unroll")                                           \
    for (int fr = 0; fr < 4; ++fr) {                                                 \
      const int rr = wm * 64 + fr * 16 + lo;                                         \
      _Pragma("unroll") for (int kk = 0; kk < 2; ++kk)                               \
        af[fr][kk] = *(const h8*)&As[db][mg][rr * 64 + (((kk * 4 + hi) ^ (rr & 7)) * 8)]; \
    } } while (0)
#define LDB(db, ng) do { _Pragma("unroll")                                           \
    for (int fc = 0; fc < 2; ++fc) {                                                 \
      const int rr = wn * 32 + fc * 16 + lo;                                         \
      _Pragma("unroll") for (int kk = 0; kk < 2; ++kk)                               \
        bf[ng][fc][kk] = *(const h8*)&Bs[db][ng][rr * 64 + (((kk * 4 + hi) ^ (rr & 7)) * 8)]; \
    } } while (0)
#define MFMA_PH(mg, ng) do {                                                         \
    __builtin_amdgcn_s_setprio(1);                                                   \
    _Pragma("unroll") for (int fr = 0; fr < 4; ++fr)                                 \
      _Pragma("unroll") for (int fc = 0; fc < 2; ++fc) {                             \
        acc[mg][fr][ng][fc] = mfma16(af[fr][0], bf[ng][fc][0], acc[mg][fr][ng][fc]); \
        acc[mg][fr][ng][fc] = mfma16(af[fr][1], bf[ng][fc][1], acc[mg][fr][ng][fc]); \
      }                                                                              \
    __builtin_amdgcn_s_setprio(0);                                                   \
  } while (0)
#define BARR do { asm volatile("" ::: "memory"); __builtin_amdgcn_s_barrier();       \
                  asm volatile("" ::: "memory"); } while (0)
#define VM8 asm volatile("s_waitcnt vmcnt(8)" ::: "memory")

  const f4 zero = {0.f, 0.f, 0.f, 0.f};
  f4 acc[2][4][2][2];
  #pragma unroll
  for (int a_ = 0; a_ < 2; ++a_)
    #pragma unroll
    for (int b_ = 0; b_ < 4; ++b_)
      #pragma unroll
      for (int c_ = 0; c_ < 2; ++c_)
        #pragma unroll
        for (int d_ = 0; d_ < 2; ++d_) acc[a_][b_][c_][d_] = zero;
  h8 af[4][2];
  h8 bf[2][2][2];

  STG_A(0, 0, 0); STG_B(0, 0, 0); STG_A(0, 1, 0); STG_B(0, 1, 0);
  STG_A(1, 0, 1); STG_B(1, 0, 1); STG_A(1, 1, 1);
  asm volatile("s_waitcnt vmcnt(4)" ::: "memory");   // covers t0 A0,B0,A1,B1 + t1.A0
  BARR;

  for (int i = 0; i < 8; ++i) {
    const int t2 = 2 * i + 2, t3 = 2 * i + 3;
    LDA(0, 0); LDB(0, 0); STG_B(1, 1, 2 * i + 1); MFMA_PH(0, 0); VM8; BARR;
    LDB(0, 1); STG_A(0, 0, t2); MFMA_PH(0, 1); BARR;
    LDA(0, 1); STG_B(0, 0, t2); MFMA_PH(1, 0); BARR;
    STG_A(0, 1, t2); MFMA_PH(1, 1); VM8; BARR;
    LDA(1, 0); LDB(1, 0); STG_B(0, 1, t2); MFMA_PH(0, 0); VM8; BARR;
    LDB(1, 1); STG_A(1, 0, t3); MFMA_PH(0, 1); BARR;
    LDA(1, 1); STG_B(1, 0, t3); MFMA_PH(1, 0); BARR;
    STG_A(1, 1, t3); MFMA_PH(1, 1); VM8; BARR;
  }

  // epilogue: per-slab consumer layout
  const int slabv = byy >> 2;
  #pragma unroll
  for (int mg = 0; mg < 2; ++mg)
    #pragma unroll
    for (int fr = 0; fr < 4; ++fr) {
      const int row0 = bm + mg * 128 + wm * 64 + fr * 16 + hi * 4;
      #pragma unroll
      for (int ng = 0; ng < 2; ++ng)
        #pragma unroll
        for (int fc = 0; fc < 2; ++fc) {
          const int colg = bn + ng * 128 + wn * 32 + fc * 16 + lo;
          const int e = colg & 1023;
          if (slabv <= 1) {
            _Float16* dst = (slabv == 0) ? Aq : Ak;
            #pragma unroll
            for (int r = 0; r < 4; ++r) {
              const int s = row0 + r;
              const long off = (long)(((s >> 7) * 256 + (s & 15) * 16 + (e >> 6))) * 512
                               + ((s >> 4) & 7) * 64 + (e & 63);
              dst[off] = (_Float16)acc[mg][fr][ng][fc][r];
            }
          } else if (slabv == 5) {
            const h2 a = cvt_pk(acc[mg][fr][ng][fc][0], acc[mg][fr][ng][fc][1]);
            const h2 b = cvt_pk(acc[mg][fr][ng][fc][2], acc[mg][fr][ng][fc][3]);
            const h4 v4 = {a[0], a[1], b[0], b[1]};
            *(h4*)&vgT[(long)e * 2048 + row0] = v4;
          } else {
            _Float16* cp = proj234 + (long)(slabv - 2) * 2097152 + (long)row0 * 1024 + e;
            #pragma unroll
            for (int r = 0; r < 4; ++r)
              cp[(long)r * 1024] = (_Float16)acc[mg][fr][ng][fc][r];
          }
        }
    }
#undef STG_A
#undef STG_B
#undef LDA
#undef LDB
#undef MFMA_PH
#undef BARR
#undef VM8
}

// ------- mega flash: compacted split-K flash (K,V LDS dbuf) + P-gemm + Vsum ------
// grid 1296: [0,1024) flash | [1024,1280) P-gemm 64^2 | [1280,1296) Vsum
// Flash LDS: K dbuf 16KB + V dbuf 16KB + Ps 10KB = 42KB.
__global__ __launch_bounds__(256) void flash_kernel(
    const _Float16* __restrict__ Q, const _Float16* __restrict__ Km,
    const _Float16* __restrict__ Vt, const int* __restrict__ qsel,
    const int* __restrict__ qcnt, _Float16* __restrict__ ctx,
    _Float16* __restrict__ pO, float2* __restrict__ ml,
    const _Float16* __restrict__ Aq, const _Float16* __restrict__ Ak,
    _Float16* __restrict__ P, const _Float16* __restrict__ vl,
    float* __restrict__ Vall, float* __restrict__ Vtail) {
  __shared__ alignas(16) char smem[43008];   // union: flash 42KB | P-gemm 16KB | Vsum 2KB
  const int bx = blockIdx.x;
  const int tid = threadIdx.x;

  if (bx >= 1280) {
    // ---- V column sums per head ----
    const int hh = bx - 1280;
    const int d = tid & 63, g = tid >> 6;
    float sall = 0.f, shead = 0.f;
    for (int i = 0; i < 32; ++i) {
      const int ro = g * 32 + i;  // 0..127
      const _Float16* base = vl + (long)(hh * 128 + ro) * 1024 + d;
      #pragma unroll
      for (int j = 0; j < 16; ++j) {
        const float v = (float)base[j * 64];
        sall += v;
        if (ro < 16) shead += v;
      }
    }
    float* sA = (float*)smem;            // [4][64]
    float* sH = (float*)(smem + 1024);   // [4][64]
    sA[g * 64 + d] = sall; sH[g * 64 + d] = shead;
    __syncthreads();
    if (g == 0) {
      const float a = sA[d] + sA[64 + d] + sA[128 + d] + sA[192 + d];
      const float hsum = sH[d] + sH[64 + d] + sH[128 + d] + sH[192 + d];
      Vall[hh * 64 + d] = a;
      Vtail[hh * 64 + d] = a - hsum;
    }
    return;
  }

  if (bx >= 1024) {
    // ---- P-gemm: P[h] = Aq[h] * Ak[h]^T, 64^2 tiles, K=512, single-buffered ----
    const int b = bx - 1024;                 // 0..255
    const int hh = b >> 4, sub = b & 15;
    const int bm = (sub >> 2) * 64, bn = (sub & 3) * 64;
    const _Float16* Ab = Aq + (long)hh * 131072;
    const _Float16* Bb = Ak + (long)hh * 131072;
    _Float16* As = (_Float16*)smem;            // [64][64]
    _Float16* Bs = (_Float16*)(smem + 8192);   // [64][64]
    const int w = tid >> 6, l = tid & 63;
    const int lo = l & 15, hi = l >> 4;
    const int srow = tid >> 3;                 // 0..31
    const int ssl = (tid & 7) ^ (srow & 7);

    const f4 zero = {0.f, 0.f, 0.f, 0.f};
    f4 acc[4];
    #pragma unroll
    for (int n = 0; n < 4; ++n) acc[n] = zero;

    for (int k0 = 0; k0 < 512; k0 += 64) {
      async_copy16(&Ab[(long)(bm + srow) * 512 + k0 + ssl * 8], &As[(w * 8) * 64]);
      async_copy16(&Ab[(long)(bm + 32 + srow) * 512 + k0 + ssl * 8], &As[(w * 8 + 32) * 64]);
      async_copy16(&Bb[(long)(bn + srow) * 512 + k0 + ssl * 8], &Bs[(w * 8) * 64]);
      async_copy16(&Bb[(long)(bn + 32 + srow) * 512 + k0 + ssl * 8], &Bs[(w * 8 + 32) * 64]);
      __syncthreads();
      #pragma unroll
      for (int kk = 0; kk < 2; ++kk) {
        const int ra = w * 16 + lo;
        const h8 af = *(const h8*)&As[ra * 64 + (((kk * 4 + hi) ^ (ra & 7)) * 8)];
        #pragma unroll
        for (int n = 0; n < 4; ++n) {
          const int rb = n * 16 + lo;
          const h8 bff = *(const h8*)&Bs[rb * 64 + (((kk * 4 + hi) ^ (rb & 7)) * 8)];
          acc[n] = mfma16(af, bff, acc[n]);
        }
      }
      __syncthreads();
    }
    #pragma unroll
    for (int n = 0; n < 4; ++n) {
      const int col = bn + n * 16 + lo;
      const int row0 = bm + w * 16 + hi * 4;
      #pragma unroll
      for (int r = 0; r < 4; ++r)
        P[(long)hh * 65536 + (long)(row0 + r) * 256 + col] = (_Float16)acc[n][r];
    }
    return;
  }

  // ---- flash ----
  const int h = bx & 15;
  const int v = bx >> 4;               // 0..63
  const int tile = 31 - (v >> 1);      // heavy-first
  const int chunk = v & 1;
  int cnt = qcnt[0];
  cnt = cnt < 1 ? 1 : (cnt > 2048 ? 2048 : cnt);   // rocprof-replay poison guard
  if (tile * 64 >= cnt) return;
  const int L = (qsel[min(tile * 64 + 63, cnt - 1)] & 2047) + 1;
  const int ntot = (L + 63) >> 6;
  const bool chunked = (ntot > 16);
  if (!chunked && chunk) return;
  const int nsplit = chunked ? ((ntot + 1) >> 1) : ntot;
  const int t0 = chunk ? nsplit : 0;
  const int t1 = chunk ? ntot : nsplit;

  const int w = tid >> 6, l = tid & 63;
  const int lo = l & 15, hi = l >> 4;
  const int row = tile * 64 + w * 16 + lo;
  const int qg = qsel[min(row, cnt - 1)] & 2047;   // orig seq position

  _Float16* KsB = (_Float16*)smem;                       // [2][4096]
  _Float16* VsB = (_Float16*)(smem + 16384);             // [2][4096]
  _Float16* ps = (_Float16*)(smem + 32768) + w * 1280;   // [16 q][80]

  const int rl = tid >> 3;              // 0..31
  const int ssl = (tid & 7) ^ (rl & 7); // source-preswizzled k-seg

#define STAGE(b, t)                                                                   \
  do {                                                                                \
    async_copy16(&Km[(long)((t) * 64 + rl) * EMB + h * DH + ssl * 8],                 \
                 &KsB[(b) * 4096 + (w * 8) * 64]);                                    \
    async_copy16(&Km[(long)((t) * 64 + 32 + rl) * EMB + h * DH + ssl * 8],            \
                 &KsB[(b) * 4096 + (w * 8 + 32) * 64]);                               \
    async_copy16(&Vt[(long)(h * DH + rl) * S_LEN + (t) * 64 + ssl * 8],               \
                 &VsB[(b) * 4096 + (w * 8) * 64]);                                    \
    async_copy16(&Vt[(long)(h * DH + 32 + rl) * S_LEN + (t) * 64 + ssl * 8],          \
                 &VsB[(b) * 4096 + (w * 8 + 32) * 64]);                               \
  } while (0)

  h8 qf[2];
  #pragma unroll
  for (int kk = 0; kk < 2; ++kk)
    qf[kk] = *(const h8*)&Q[(long)qg * EMB + h * DH + kk * 32 + hi * 8];

  const f4 zero = {0.f, 0.f, 0.f, 0.f};
  f4 o[4];
  #pragma unroll
  for (int nd = 0; nd < 4; ++nd) o[nd] = zero;
  float mr = -1e30f, lr = 0.f;
  const float SC = 0.125f * 1.44269504f;   // scale folded into log2 domain

  STAGE(0, t0);
  __syncthreads();
  int cur = 0;

  for (int t = t0; t < t1; ++t) {
    if (t + 1 < t1) STAGE(cur ^ 1, t + 1);   // prefetch next tile (async)

    const _Float16* ks = KsB + cur * 4096;
    const _Float16* vs = VsB + cur * 4096;

    // ---- QK^T (S^T = K x Q) ----
    __builtin_amdgcn_s_setprio(1);
    f4 s[4];
    #pragma unroll
    for (int n = 0; n < 4; ++n) {
      s[n] = zero;
      #pragma unroll
      for (int kk = 0; kk < 2; ++kk) {
        const int r = n * 16 + lo;
        const h8 kf = *(const h8*)&ks[r * 64 + (((kk * 4 + hi) ^ (lo & 7)) * 8)];
        s[n] = mfma16(kf, qf[kk], s[n]);
      }
    }
    __builtin_amdgcn_s_setprio(0);

    // ---- online softmax (log2 domain), q lane-local, causal vs qg ----
    float sv[16];
    float tm = -1e30f;
    #pragma unroll
    for (int n = 0; n < 4; ++n)
      #pragma unroll
      for (int r = 0; r < 4; ++r) {
        float vv = s[n][r] * SC;
        if ((t * 64 + n * 16 + hi * 4 + r) > qg) vv = -1e30f;
        sv[n * 4 + r] = vv;
        tm = fmaxf(tm, vv);
      }
    tm = fmaxf(tm, __shfl_xor(tm, 16));
    tm = fmaxf(tm, __shfl_xor(tm, 32));
    const float mn = fmaxf(mr, tm);
    const float c = exp2f(mr - mn);
    mr = mn;
    float psum = 0.f;
    #pragma unroll
    for (int i = 0; i < 16; ++i) {
      sv[i] = exp2f(sv[i] - mr);
      psum += sv[i];
    }
    psum += __shfl_xor(psum, 16);
    psum += __shfl_xor(psum, 32);
    lr = lr * c + psum;

    // ---- pack P^T -> ps[q][key] (row stride 80, XOR-swizzled 16B segs) ----
    #pragma unroll
    for (int n = 0; n < 4; ++n) {
      const int seg = (2 * n + (hi >> 1)) ^ (lo & 7);
      const int base = lo * 80 + seg * 8 + (hi & 1) * 4;
      *(h2*)&ps[base] = cvt_pk(sv[n * 4 + 0], sv[n * 4 + 1]);
      *(h2*)&ps[base + 2] = cvt_pk(sv[n * 4 + 2], sv[n * 4 + 3]);
    }
    h8 pb[2];
    #pragma unroll
    for (int kk = 0; kk < 2; ++kk)
      pb[kk] = *(const h8*)&ps[lo * 80 + (((kk * 4 + hi) ^ (lo & 7)) * 8)];

    // ---- PV: O^T[d][q] += V^T x P ----
    __builtin_amdgcn_s_setprio(1);
    #pragma unroll
    for (int nd = 0; nd < 4; ++nd) {
      #pragma unroll
      for (int r = 0; r < 4; ++r) o[nd][r] *= c;
      #pragma unroll
      for (int kk = 0; kk < 2; ++kk) {
        const int rr = nd * 16 + lo;
        const h8 vf = *(const h8*)&vs[rr * 64 + (((kk * 4 + hi) ^ (lo & 7)) * 8)];
        o[nd] = mfma16(vf, pb[kk], o[nd]);
      }
    }
    __builtin_amdgcn_s_setprio(0);

    __syncthreads();   // drains prefetch + guards buffer reuse
    cur ^= 1;
  }
#undef STAGE

  if (chunked) {
    const int slot = (h * 32 + tile) * 2 + chunk;
    _Float16* po = pO + (long)slot * 4096 + (w * 16 + lo) * 64;
    #pragma unroll
    for (int nd = 0; nd < 4; ++nd) {
      const h2 a = cvt_pk(o[nd][0], o[nd][1]);
      const h2 b = cvt_pk(o[nd][2], o[nd][3]);
      const h4 v4 = {a[0], a[1], b[0], b[1]};
      *(h4*)&po[nd * 16 + hi * 4] = v4;
    }
    if (hi == 0) ml[slot * 64 + w * 16 + lo] = make_float2(mr, lr);
  } else if (row < cnt) {
    const float inv = 1.f / lr;
    #pragma unroll
    for (int nd = 0; nd < 4; ++nd) {
      const h2 a = cvt_pk(o[nd][0] * inv, o[nd][1] * inv);
      const h2 b = cvt_pk(o[nd][2] * inv, o[nd][3] * inv);
      const h4 v4 = {a[0], a[1], b[0], b[1]};
      *(h4*)&ctx[(long)qg * EMB + h * DH + nd * 16 + hi * 4] = v4;
    }
  }
}

// ------- fused finish: local softmax rows + split-K combine + uniform tail -------
__global__ __launch_bounds__(256) void localfin_kernel(
    const _Float16* __restrict__ P, const _Float16* __restrict__ vl,
    const float* __restrict__ Vall, const float* __restrict__ Vtail,
    const _Float16* __restrict__ pO, const float2* __restrict__ ml,
    const int* __restrict__ gmask, const int* __restrict__ qsel,
    const int* __restrict__ qcnt, _Float16* __restrict__ ctx) {
  const int bid = blockIdx.x;
  const int tid = threadIdx.x;
  if (bid < 1024) {
    // rows q<256, gmask==0: per-64-lane-group head; 4 heads per block
    const int q = bid & 255, hg = bid >> 8;
    if (gmask[q] == 1) return;
    const int sub = tid >> 6, l = tid & 63;
    const int hh = hg * 4 + sub;
    __shared__ float wgt[4][256];
    const _Float16* Pr = P + ((long)hh * 256 + q) * 256;
    float sv[4];
    bool valid[4];
    float M = -1e30f;
    #pragma unroll
    for (int i = 0; i < 4; ++i) {
      const int k = l + i * 64;
      valid[i] = (k <= q);
      sv[i] = valid[i] ? (float)Pr[k] * 0.015625f : -1e30f;  // (1/8 mean)*(1/8 scale)
      M = fmaxf(M, sv[i]);
    }
    M = fmaxf(M, __shfl_xor(M, 1));
    M = fmaxf(M, __shfl_xor(M, 2));
    M = fmaxf(M, __shfl_xor(M, 4));
    M = fmaxf(M, __shfl_xor(M, 8));
    M = fmaxf(M, __shfl_xor(M, 16));
    M = fmaxf(M, __shfl_xor(M, 32));
    M = fmaxf(M, 0.f);   // 1792 zero-pad entries participate
    float ps = 0.f;
    #pragma unroll
    for (int i = 0; i < 4; ++i) {
      const float e = valid[i] ? __expf(sv[i] - M) : 0.f;
      wgt[sub][l + i * 64] = e;
      ps += e;
    }
    ps += __shfl_xor(ps, 1);
    ps += __shfl_xor(ps, 2);
    ps += __shfl_xor(ps, 4);
    ps += __shfl_xor(ps, 8);
    ps += __shfl_xor(ps, 16);
    ps += __shfl_xor(ps, 32);
    const float em = __expf(-M);
    const float denom = ps + 1792.f * em;
    const int d = l;
    float acc = em * Vtail[hh * 64 + d];
    const _Float16* vb = vl + (long)hh * 128 * 1024 + d;
    for (int k = 0; k <= q; ++k)
      acc += wgt[sub][k] * (float)vb[(long)(k >> 4) * 1024 + (k & 15) * 64];
    ctx[(long)q * EMB + hh * DH + d] = (_Float16)(acc / denom);
    return;
  }
  if (bid < 1536) {
    // split-K combine for chunked compacted tiles
    const int b2 = bid - 1024;              // 0..511
    const int h = b2 & 15, tile = b2 >> 4;  // tile 0..31
    int cnt = qcnt[0];
    cnt = cnt < 1 ? 1 : (cnt > 2048 ? 2048 : cnt);   // rocprof-replay poison guard
    if (tile * 64 >= cnt) return;
    const int L = (qsel[min(tile * 64 + 63, cnt - 1)] & 2047) + 1;
    if (((L + 63) >> 6) <= 16) return;      // direct-written by flash
    const int q = tid >> 2, ds = (tid & 3) * 16;
    const int row = tile * 64 + q;
    if (row >= cnt) return;
    const int sg = qsel[row] & 2047;
    const int slot0 = (h * 32 + tile) * 2, slot1 = slot0 + 1;
    const float2 ml0 = ml[slot0 * 64 + q];
    const float2 ml1 = ml[slot1 * 64 + q];
    const float M = fmaxf(ml0.x, ml1.x);
    const float w0 = exp2f(ml0.x - M), w1 = exp2f(ml1.x - M);
    const float inv = 1.f / (w0 * ml0.y + w1 * ml1.y);
    const h8 a0 = *(const h8*)&pO[(long)slot0 * 4096 + q * 64 + ds];
    const h8 a1 = *(const h8*)&pO[(long)slot0 * 4096 + q * 64 + ds + 8];
    const h8 b0 = *(const h8*)&pO[(long)slot1 * 4096 + q * 64 + ds];
    const h8 b1 = *(const h8*)&pO[(long)slot1 * 4096 + q * 64 + ds + 8];
    h8 r0, r1;
    #pragma unroll
    for (int j = 0; j < 8; ++j) {
      r0[j] = (_Float16)((w0 * (float)a0[j] + w1 * (float)b0[j]) * inv);
      r1[j] = (_Float16)((w0 * (float)a1[j] + w1 * (float)b1[j]) * inv);
    }
    *(h8*)&ctx[(long)sg * EMB + h * DH + ds] = r0;
    *(h8*)&ctx[(long)sg * EMB + h * DH + ds + 8] = r1;
    return;
  }
  // tail: rows q>=256, gmask==0 -> Vall/2048 (8 f16 per thread)
  const int gid = (bid - 1536) * 256 + tid;   // x8 elements
  const int s = 256 + (gid >> 7), e8 = (gid & 127) * 8;
  if (gmask[s] == 0) {
    h8 v;
    #pragma unroll
    for (int j = 0; j < 8; ++j)
      v[j] = (_Float16)(Vall[e8 + j] * (1.f / 2048.f));
    *(h8*)&ctx[(long)s * EMB + e8] = v;
  }
}

// ---------------- final projection: 64x64 tile, double-buffered, 512 blocks -------
__global__ __launch_bounds__(256) void gemm64_kernel(
    const _Float16* __restrict__ A, const _Float16* __restrict__ Bt,
    float* __restrict__ C, const float* __restrict__ bias) {
  const int bm = blockIdx.x * 64, bn = blockIdx.y * 64;
  __shared__ alignas(16) _Float16 As[2][4096];
  __shared__ alignas(16) _Float16 Bs[2][4096];
  const int tid = threadIdx.x;
  const int w = tid >> 6, l = tid & 63;
  const int lo = l & 15, hi = l >> 4;
  const int srow = tid >> 3;             // 0..31
  const int ssl = (tid & 7) ^ (srow & 7);

#define STG64(b, k0) do {                                                            \
    async_copy16(&A[(long)(bm + srow) * 1024 + (k0) + ssl * 8], &As[b][(w * 8) * 64]); \
    async_copy16(&A[(long)(bm + 32 + srow) * 1024 + (k0) + ssl * 8],                 \
                 &As[b][(w * 8 + 32) * 64]);                                         \
    async_copy16(&Bt[(long)(bn + srow) * 1024 + (k0) + ssl * 8], &Bs[b][(w * 8) * 64]); \
    async_copy16(&Bt[(long)(bn + 32 + srow) * 1024 + (k0) + ssl * 8],                \
                 &Bs[b][(w * 8 + 32) * 64]);                                         \
  } while (0)

  const f4 zero = {0.f, 0.f, 0.f, 0.f};
  f4 acc[4];
  #pragma unroll
  for (int n = 0; n < 4; ++n) acc[n] = zero;

  STG64(0, 0);
  __syncthreads();
  int cur = 0;
  for (int k0 = 0; k0 < 1024; k0 += 64) {
    if (k0 + 64 < 1024) STG64(cur ^ 1, k0 + 64);
    #pragma unroll
    for (int kk = 0; kk < 2; ++kk) {
      const int ra = w * 16 + lo;
      const h8 af = *(const h8*)&As[cur][ra * 64 + (((kk * 4 + hi) ^ (ra & 7)) * 8)];
      #pragma unroll
      for (int n = 0; n < 4; ++n) {
        const int rb = n * 16 + lo;
        const h8 bff = *(const h8*)&Bs[cur][rb * 64 + (((kk * 4 + hi) ^ (rb & 7)) * 8)];
        acc[n] = mfma16(af, bff, acc[n]);
      }
    }
    __syncthreads();
    cur ^= 1;
  }
#undef STG64

  #pragma unroll
  for (int n = 0; n < 4; ++n) {
    const int col = bn + n * 16 + lo;
    const float bv = bias[col];
    const int row0 = bm + w * 16 + hi * 4;
    #pragma unroll
    for (int r = 0; r < 4; ++r)
      C[(long)(row0 + r) * 1024 + col] = acc[n][r] + bv;
  }
}

// ---------------- launcher ----------------
extern "C" void kernel_launch(void* const* d_in, const int* in_sizes, int n_in,
                              void* d_out, int out_size, void* d_ws, size_t ws_size,
                              hipStream_t stream) {
  const float* x = (const float*)d_in[0];
  const int* gmask = (const int*)d_in[1];
  const float* Wlq = (const float*)d_in[2];
  const float* Wlk = (const float*)d_in[3];
  const float* Wlv = (const float*)d_in[4];
  const float* Wq = (const float*)d_in[5];
  const float* Wk = (const float*)d_in[6];
  const float* Wv = (const float*)d_in[7];
  const float* Wp = (const float*)d_in[8];
  const float* bp = (const float*)d_in[9];
  float* out = (float*)d_out;

  char* ws = (char*)d_ws;
  _Float16* xh = (_Float16*)(ws);                    // [0,4)  prep->gemm256; then pO
  _Float16* Wtb = (_Float16*)(ws + (4u << 20));      // [4,18) prep->gemm256
  _Float16* pO = (_Float16*)(ws);                    // [0,8)  flash->localfin
  _Float16* ctx = (_Float16*)(ws + (8u << 20));      // [8,12)
  _Float16* P = (_Float16*)(ws + (12u << 20));       // [12,14)
  float* Vall = (float*)(ws + (14u << 20));          // [14,16)
  float* Vtail = (float*)(ws + (14u << 20) + 4096);
  float2* ml = (float2*)(ws + (14u << 20) + 16384);  // 512KB
  _Float16* Wpt = (_Float16*)(ws + (16u << 20));     // [16,18) prep->gemm64
  _Float16* Aq = (_Float16*)(ws + (18u << 20));      // [18,22) gemm256->flash
  _Float16* Ak = (_Float16*)(ws + (22u << 20));      // [22,26)
  _Float16* proj234 = (_Float16*)(ws + (26u << 20)); // [26,38) vl,qg,kg
  _Float16* vl = proj234;                            // [26,30)
  _Float16* qg = (_Float16*)(ws + (30u << 20));      // [30,34)
  _Float16* kg = (_Float16*)(ws + (34u << 20));      // [34,38)
  _Float16* vgT = (_Float16*)(ws + (38u << 20));     // [38,42)
  int* qsel = (int*)(ws + (42u << 20));
  int* qcnt = (int*)(ws + (42u << 20) + 8192);

  prep_kernel<<<9217, 256, 0, stream>>>(x, Wlq, Wlk, Wlv, Wq, Wk, Wv, Wp, xh, Wtb,
                                        gmask, qsel, qcnt);
  gemm256_kernel<<<192, 512, 0, stream>>>(xh, Wtb, Aq, Ak, proj234, vgT);
  flash_kernel<<<1296, 256, 0, stream>>>(qg, kg, vgT, qsel, qcnt, ctx, pO, ml,
                                         Aq, Ak, P, vl, Vall, Vtail);
  localfin_kernel<<<2432, 256, 0, stream>>>(P, vl, Vall, Vtail, pO, ml, gmask,
                                            qsel, qcnt, ctx);
  gemm64_kernel<<<dim3(32, 16), 256, 0, stream>>>(ctx, Wpt, out, bp);
}